// Round 13
// baseline (346.682 us; speedup 1.0000x reference)
//
#include <hip/hip_runtime.h>
#include <math.h>

// FourRegionAttention on MI355X (gfx950). B=64, n=2304 (48x48), D=64, h=8, hd=8.
// 3-kernel pipeline: k_pre (fused setup1+setupW+lnkv; setup blocks FIRST;
// KT/VT staged through XOR-swizzled LDS for coalesced stores) -> k_prefix
// (512 blocks, one per bh) -> k_main (16-tok blocks, fragment-swizzled G/Z,
// XCD-chunked blockIdx swizzle [FETCH 94->41MB, r12], 2-iteration phases
// with double-buffered Tlds/CB: 5 barriers/block instead of 9).
// k_main A-fragments re-read from LDS per iteration (r7 hoist regressed).
// NOTE: no min-waves arg on __launch_bounds__ (spill hazard, r1-r2).

#define SCALE_W  0.3535533905932738f   // 8^-0.5
#define SCALE_RA 0.3535533905932738f
#define LN_EPS 1e-5f

typedef __attribute__((ext_vector_type(8))) short bf16x8;
typedef __attribute__((ext_vector_type(4))) float f32x4;

// ---- workspace layout (float offsets) ----
#define OFF_XN   0ull
#define SZ_XN    (64ull*2304*64)            // 9437184
#define OFF_KT   (OFF_XN + SZ_XN)           // k_t [b][h][n][8]
#define SZ_KT    (64ull*8*2304*8)           // 9437184
#define OFF_VT   (OFF_KT + SZ_KT)           // v_t [b][h][n][8]
#define OFF_PA   (OFF_VT + SZ_KT)           // PA [bh][2401][5]: e, e*v[0..3] prefix
#define SZ_PA    (512ull*2401*5)
#define OFF_PB   (OFF_PA + SZ_PA)           // PB [bh][2401][4]: e*v[4..7] prefix
#define SZ_PB    (512ull*2401*4)
#define OFF_ECLS (OFF_PB + SZ_PB)           // 512
#define OFF_QC   (OFF_ECLS + 512)           // 64 (scaled q_c)
#define OFF_KC   (OFF_QC + 64)              // 64
#define OFF_VC   (OFF_KC + 64)              // 64
#define OFF_CLOG (OFF_VC + 64)              // 8
#define OFF_BK   (OFF_CLOG + 8)             // 64  (dead - kept for layout)
#define OFF_BV   (OFF_BK + 64)              // 64
#define OFF_AH   (OFF_BV + 64)              // 512 a_h = Wraq@bqkv_h
#define OFF_W1   (OFF_AH + 512)             // 64  (dead - kept for layout)
#define OFF_WZ   (OFF_W1 + 64)              // 64  Wrao@bv
#define OFF_B2   (OFF_WZ + 64)              // 512 Wrak^T@a_h
#define OFF_V2   (OFF_B2 + 512)             // 512 v2_h
#define OFF_UH   (OFF_V2 + 512)             // 512 (dead - kept for layout)
#define OFF_CH   (OFF_UH + 512)             // 8   (dead - kept for layout)
#define OFF_C1   (OFF_CH + 8)               // 64  const output bias
// GB/ZB: per head 8192 ushorts = 16 records x 512 ushorts (1KB each).
// record idx within head: tile(e>>4)*2048 + half(d>>5)*1024 + plane*512,
// entry: lane = ((d>>3)&3)*16 + (e&15), j = d&7  (fragment lane-major).
#define OFF_G    (OFF_C1 + 64)              // 32768 floats
#define OFF_Z    (OFF_G + 32768)            // 32768 floats

__device__ inline void split2(float x, unsigned short &h, unsigned short &l) {
  unsigned u = __float_as_uint(x);
  unsigned hr = (u + 0x7fffu + ((u >> 16) & 1u)) >> 16;
  h = (unsigned short)hr;
  float hf = __uint_as_float(hr << 16);
  float lo = x - hf;
  unsigned u2 = __float_as_uint(lo);
  l = (unsigned short)((u2 + 0x7fffu + ((u2 >> 16) & 1u)) >> 16);
}

// split a pair of floats into packed bf16 hi words + packed bf16 lo-residual
// words using the HW packed converter (RNE, same rounding as split2).
__device__ inline void split2x2(float x0, float x1, unsigned &h, unsigned &l) {
  asm("v_cvt_pk_bf16_f32 %0, %1, %2" : "=v"(h) : "v"(x0), "v"(x1));
  float r0 = x0 - __uint_as_float(h << 16);
  float r1 = x1 - __uint_as_float(h & 0xffff0000u);
  asm("v_cvt_pk_bf16_f32 %0, %1, %2" : "=v"(l) : "v"(r0), "v"(r1));
}

__device__ inline float dot64(const float* __restrict__ a, const float* __restrict__ b) {
  float s0 = 0.f, s1 = 0.f, s2 = 0.f, s3 = 0.f;
  #pragma unroll
  for (int d = 0; d < 64; d += 4) {
    float4 av = *(const float4*)(a + d);
    float4 bv = *(const float4*)(b + d);
    s0 += av.x * bv.x; s1 += av.y * bv.y;
    s2 += av.z * bv.z; s3 += av.w * bv.w;
  }
  return (s0 + s1) + (s2 + s3);
}

// ---------------- fused pre-kernel: setup1 (blk 0) | setupW (1..16) | lnkv (17..2320) ----------------
__global__ __launch_bounds__(256) void k_pre(const float* __restrict__ x,
      const float* __restrict__ ln_g, const float* __restrict__ ln_b,
      const float* __restrict__ Wqkv, const float* __restrict__ bqkv,
      const float* __restrict__ cls_tok, const float* __restrict__ Wwqkv,
      const float* __restrict__ bwqkv, const float* __restrict__ Wwproj,
      const float* __restrict__ bwproj, const float* __restrict__ Wraq,
      const float* __restrict__ Wrak, const float* __restrict__ Wrav,
      const float* __restrict__ Wrao, const float* __restrict__ brao,
      const float* __restrict__ Wout, const float* __restrict__ bout,
      float* __restrict__ ws) {
  __shared__ float smu[12928];   // union: lnkv 12928 | setupW 8320 | setup1 64 | kv-stage 8192
  int tid = threadIdx.x;
  int blk = blockIdx.x;

  if (blk >= 17) {
    // ======== LayerNorm + k/v GEMM ========
    float* xnT = smu;                 // [d][68]
    float* xt  = smu + 4352;          // [tok][65]
    float* wkv = smu + 4352;          // [d][132]
    float* muL = smu + 4352 + 8448;
    float* rsL = muL + 64;

    long T0 = (long)(blk - 17) * 64;
    int tok = tid >> 2, seg = tid & 3;

    const float4* x4 = (const float4*)(x + (T0 + tok)*64 + seg*16);
    float4 va = x4[0], vb = x4[1], vc4 = x4[2], vd = x4[3];
    {
      float* xp = xt + tok*65 + seg*16;
      xp[0]=va.x; xp[1]=va.y; xp[2]=va.z; xp[3]=va.w;
      xp[4]=vb.x; xp[5]=vb.y; xp[6]=vb.z; xp[7]=vb.w;
      xp[8]=vc4.x; xp[9]=vc4.y; xp[10]=vc4.z; xp[11]=vc4.w;
      xp[12]=vd.x; xp[13]=vd.y; xp[14]=vd.z; xp[15]=vd.w;
    }
    __syncthreads();
    if (tid < 64) {
      float s = 0.f;
      for (int i2 = 0; i2 < 64; ++i2) s += xt[tid*65 + i2];
      float mu = s * (1.0f/64.0f);
      float v = 0.f;
      for (int i2 = 0; i2 < 64; ++i2) { float d = xt[tid*65 + i2] - mu; v += d*d; }
      v *= (1.0f/64.0f);
      muL[tid] = mu; rsL[tid] = 1.0f / sqrtf(v + LN_EPS);
    }
    __syncthreads();
    {
      float mu = muL[tok], rs = rsL[tok];
      float xv[16];
      #pragma unroll
      for (int k = 0; k < 16; ++k) {
        int i2 = seg*16 + k;
        float v = (xt[tok*65 + i2] - mu) * rs * ln_g[i2] + ln_b[i2];
        xv[k] = v;
        xnT[i2*68 + tok] = v;
      }
      float4* xng = (float4*)(ws + OFF_XN + (T0 + tok)*64 + seg*16);
      xng[0] = make_float4(xv[0], xv[1], xv[2], xv[3]);
      xng[1] = make_float4(xv[4], xv[5], xv[6], xv[7]);
      xng[2] = make_float4(xv[8], xv[9], xv[10], xv[11]);
      xng[3] = make_float4(xv[12], xv[13], xv[14], xv[15]);
    }
    __syncthreads();
    {
      int o = tid >> 1, dh = (tid & 1) * 32;
      #pragma unroll
      for (int k = 0; k < 32; k += 4) {
        float4 w4 = *(const float4*)(Wwqkv + (64 + o)*64 + dh + k);
        wkv[(dh+k+0)*132 + o] = w4.x;
        wkv[(dh+k+1)*132 + o] = w4.y;
        wkv[(dh+k+2)*132 + o] = w4.z;
        wkv[(dh+k+3)*132 + o] = w4.w;
      }
    }
    __syncthreads();
    int tokq = tid & 15, og = tid >> 4;
    float acc[4][8];
    #pragma unroll
    for (int ti = 0; ti < 4; ++ti)
      #pragma unroll
      for (int k = 0; k < 8; ++k) acc[ti][k] = 0.f;
    for (int d2 = 0; d2 < 64; ++d2) {
      float4 a4 = *(float4*)&xnT[d2*68 + tokq*4];
      float4 b0 = *(float4*)&wkv[d2*132 + og*8];
      float4 b1 = *(float4*)&wkv[d2*132 + og*8 + 4];
      float aa[4] = {a4.x, a4.y, a4.z, a4.w};
      float bbv[8] = {b0.x,b0.y,b0.z,b0.w,b1.x,b1.y,b1.z,b1.w};
      #pragma unroll
      for (int ti = 0; ti < 4; ++ti)
        #pragma unroll
        for (int k = 0; k < 8; ++k) acc[ti][k] += aa[ti]*bbv[k];
    }
    float bsv[8];
    #pragma unroll
    for (int k = 0; k < 8; ++k) bsv[k] = bwqkv[64 + og*8 + k];
    // ---- stage into XOR-swizzled LDS, then fully-coalesced global stores ----
    __syncthreads();                       // all xnT/wkv reads done
    float4* kvb = (float4*)smu;            // 2048 float4 = 8192 floats
    #pragma unroll
    for (int ti = 0; ti < 4; ++ti) {
      int ntok = tokq*4 + ti;
      int L0 = og*128 + ntok*2;
      int p0 = L0 ^ ((L0 >> 3) & 7);
      int p1 = (L0 + 1) ^ (((L0 + 1) >> 3) & 7);
      kvb[p0] = make_float4(acc[ti][0]+bsv[0], acc[ti][1]+bsv[1], acc[ti][2]+bsv[2], acc[ti][3]+bsv[3]);
      kvb[p1] = make_float4(acc[ti][4]+bsv[4], acc[ti][5]+bsv[5], acc[ti][6]+bsv[6], acc[ti][7]+bsv[7]);
    }
    __syncthreads();
    int bb = (int)(T0 / 2304);
    int nlbase = (int)(T0 % 2304);
    #pragma unroll
    for (int r = 0; r < 8; ++r) {
      int L = tid + r*256;
      int ogr = L >> 7;
      int hhr = ogr & 7;
      int ntok = (L >> 1) & 63;
      int cc = L & 1;
      int phys = L ^ ((L >> 3) & 7);
      float4 val = kvb[phys];
      unsigned long long dstoff = (ogr < 8) ? OFF_KT : OFF_VT;
      float* dst = ws + dstoff + ((long)(bb*8 + hhr)*2304 + (nlbase + ntok))*8 + cc*4;
      *(float4*)dst = val;
    }
  } else if (blk >= 1) {
    // ======== per-head G/Z chains -> fragment-swizzled bf16 ========
    float* A  = smu;
    float* Bl = smu + 4160;
    int wblk = blk - 1;
    if (wblk < 8) {
      int hh = wblk;
      for (int o = tid; o < 4096; o += 256) {
        int d = o & 63, e = o >> 6; float s = 0.f;
        for (int f = 0; f < 64; ++f) s += Wraq[f*64+d] * Wrak[f*64+e];
        A[d*65 + e] = s;
      }
      __syncthreads();
      for (int o = tid; o < 4096; o += 256) {
        int j = o & 63, i = o >> 6; float s = 0.f;
        for (int f = 0; f < 64; ++f) s += A[i*65 + f] * Wwproj[f*64 + j];
        Bl[i*65 + j] = s;
      }
      __syncthreads();
      unsigned short* gb = (unsigned short*)(ws + OFF_G) + hh*8192;
      for (int o = tid; o < 4096; o += 256) {
        int d = o & 63, e = o >> 6; float s = 0.f;
        for (int f = 0; f < 64; ++f) s += Wqkv[(hh*64+f)*64 + d] * Bl[f*65 + e];
        unsigned short h16, l16;
        split2(s, h16, l16);
        int base = (e >> 4)*2048 + (d >> 5)*1024 + (((d >> 3) & 3)*16 + (e & 15))*8 + (d & 7);
        gb[base]       = h16;   // plane hi
        gb[base + 512] = l16;   // plane lo
      }
    } else {
      int hh = wblk - 8;
      for (int o = tid; o < 4096; o += 256) {
        int d = o & 63, e = o >> 6; float s = 0.f;
        for (int f = 0; f < 64; ++f) s += Wrav[e*64+f] * Wwproj[f*64+d];
        A[e*65 + d] = s;
      }
      __syncthreads();
      for (int o = tid; o < 4096; o += 256) {
        int d = o & 63, i = o >> 6; float s = 0.f;
        for (int f = 0; f < 64; ++f) s += Wrao[i*64+f] * A[f*65 + d];
        Bl[i*65 + d] = s;
      }
      __syncthreads();
      unsigned short* zb = (unsigned short*)(ws + OFF_Z) + hh*8192;
      for (int o = tid; o < 4096; o += 256) {
        int d = o & 63, e = o >> 6; float s = 0.f;  // d = channel, e = out-dim
        for (int f = 0; f < 64; ++f) s += Wout[e*512 + hh*64 + f] * Bl[f*65 + d];
        unsigned short h16, l16;
        split2(s, h16, l16);
        int base = (e >> 4)*2048 + (d >> 5)*1024 + (((d >> 3) & 3)*16 + (e & 15))*8 + (d & 7);
        zb[base]       = h16;
        zb[base + 512] = l16;
      }
    }
  } else {
    // ======== small folded vectors (single block) ========
    float* bwz = smu;
    for (int idx = tid; idx < 768; idx += 256) {
      if (idx < 192) {
        float s = bwqkv[idx] + dot64(Wwqkv + idx*64, cls_tok);
        if (idx < 64) ws[OFF_QC + idx] = s * SCALE_W;
        else if (idx < 128) ws[OFF_KC + idx - 64] = s;
        else ws[OFF_VC + idx - 128] = s;
      } else if (idx < 256) {
        int e = idx - 192;
        ws[OFF_BV + e] = dot64(Wrav + e*64, bwproj);
      } else {
        int t2 = idx - 256; int hh = t2 >> 6, e = t2 & 63;
        ws[OFF_AH + t2] = dot64(Wraq + e*64, bqkv + hh*64);
      }
    }
    __syncthreads();
    for (int idx = tid; idx < 584; idx += 256) {
      if (idx < 8) {
        float s = 0.f;
        for (int u = 0; u < 8; ++u) s += ws[OFF_QC + idx*8+u] * ws[OFF_KC + idx*8+u];
        ws[OFF_CLOG + idx] = s;
      } else if (idx < 72) {
        int e = idx - 8;
        ws[OFF_WZ + e] = dot64(Wrao + e*64, ws + OFF_BV);
      } else {
        int t2 = idx - 72; int hh = t2 >> 6, e = t2 & 63; float s = 0.f;
        for (int d = 0; d < 64; ++d) s += Wrak[d*64+e] * ws[OFF_AH + hh*64+d];
        ws[OFF_B2 + t2] = s;
      }
    }
    __syncthreads();
    if (tid < 64) bwz[tid] = brao[tid] + ws[OFF_WZ + tid];
    __syncthreads();
    for (int idx = tid; idx < 576; idx += 256) {
      if (idx < 512) {
        int hh = idx >> 6, e = idx & 63; float s = 0.f;
        for (int d = 0; d < 64; ++d) s += Wwproj[d*64+e] * ws[OFF_B2 + hh*64+d];
        ws[OFF_V2 + idx] = s;
      } else {
        int e = idx - 512;
        float s0 = 0.f, s1 = 0.f, s2 = 0.f, s3 = 0.f;
        for (int f = 0; f < 512; f += 4) {
          float4 w4 = *(const float4*)(Wout + e*512 + f);
          float4 b4 = *(const float4*)&bwz[f & 63];
          s0 += w4.x*b4.x; s1 += w4.y*b4.y; s2 += w4.z*b4.z; s3 += w4.w*b4.w;
        }
        ws[OFF_C1 + e] = bout[e] + (s0 + s1) + (s2 + s3);
      }
    }
  }
}

// ---------------- logits + softmax-normalizer + 2D prefix sums ----------------
__global__ __launch_bounds__(512) void k_prefix(float* __restrict__ ws) {
  __shared__ float Pp[49*49*5];
  __shared__ float red[8];
  int tid = threadIdx.x;
  int bh = blockIdx.x;
  int hh = bh & 7;
  const float* kt = ws + OFF_KT + (long)bh*2304*8;
  const float* vt = ws + OFF_VT + (long)bh*2304*8;
  float qc[8];
  #pragma unroll
  for (int u = 0; u < 8; ++u) qc[u] = ws[OFF_QC + hh*8 + u];
  float ev[5];
  float mloc = -1e30f;
  #pragma unroll
  for (int it = 0; it < 5; ++it) {
    int nn = tid + it*512;
    if (nn < 2304) {
      const float4* kk = (const float4*)(kt + nn*8);
      float4 k0 = kk[0], k1 = kk[1];
      float lv = qc[0]*k0.x + qc[1]*k0.y + qc[2]*k0.z + qc[3]*k0.w
               + qc[4]*k1.x + qc[5]*k1.y + qc[6]*k1.z + qc[7]*k1.w;
      ev[it] = lv;
      mloc = fmaxf(mloc, lv);
    }
  }
  #pragma unroll
  for (int mk = 1; mk < 64; mk <<= 1) mloc = fmaxf(mloc, __shfl_xor(mloc, mk, 64));
  if ((tid & 63) == 0) red[tid >> 6] = mloc;
  __syncthreads();
  float m = fmaxf(fmaxf(fmaxf(red[0], red[1]), fmaxf(red[2], red[3])),
                  fmaxf(fmaxf(red[4], red[5]), fmaxf(red[6], red[7])));
  m = fmaxf(m, ws[OFF_CLOG + hh]);
  if (tid == 0) ws[OFF_ECLS + bh] = __expf(ws[OFF_CLOG + hh] - m);
  #pragma unroll
  for (int it = 0; it < 5; ++it) {
    int nn = tid + it*512;
    if (nn < 2304) ev[it] = __expf(ev[it] - m);
  }
  // ---- pass A: columns [e, e*v0..3] ----
  #pragma unroll
  for (int it = 0; it < 5; ++it) {
    int nn = tid + it*512;
    if (nn < 2304) {
      int i2 = nn / 48, j2 = nn % 48;
      float4 v4 = *(const float4*)(vt + nn*8);
      float* cell = &Pp[((i2+1)*49 + (j2+1))*5];
      float e0 = ev[it];
      cell[0] = e0; cell[1] = e0*v4.x; cell[2] = e0*v4.y; cell[3] = e0*v4.z; cell[4] = e0*v4.w;
    }
  }
  __syncthreads();
  if (tid < 240) {
    int j2 = tid / 5 + 1, c = tid % 5;
    float s = 0.f;
    for (int i0 = 1; i0 <= 48; i0 += 8) {
      float v[8];
      #pragma unroll
      for (int k = 0; k < 8; ++k) v[k] = Pp[((i0+k)*49 + j2)*5 + c];
      #pragma unroll
      for (int k = 0; k < 8; ++k) { s += v[k]; v[k] = s; }
      #pragma unroll
      for (int k = 0; k < 8; ++k) Pp[((i0+k)*49 + j2)*5 + c] = v[k];
    }
  }
  __syncthreads();
  if (tid < 240) {
    int i2 = tid / 5 + 1, c = tid % 5;
    float s = 0.f;
    for (int j0 = 1; j0 <= 48; j0 += 8) {
      float v[8];
      #pragma unroll
      for (int k = 0; k < 8; ++k) v[k] = Pp[(i2*49 + j0+k)*5 + c];
      #pragma unroll
      for (int k = 0; k < 8; ++k) { s += v[k]; v[k] = s; }
      #pragma unroll
      for (int k = 0; k < 8; ++k) Pp[(i2*49 + j0+k)*5 + c] = v[k];
    }
  }
  __syncthreads();
  {
    float* pa = ws + OFF_PA + (long)bh*12005;
    for (int idx = tid; idx < 12005; idx += 512) {
      int cell = idx / 5;
      int ii = cell / 49, jj = cell % 49;
      pa[idx] = (ii && jj) ? Pp[idx] : 0.f;
    }
  }
  __syncthreads();
  // ---- pass B: columns [e*v4..7] (stride-5 layout, 4 used) ----
  #pragma unroll
  for (int it = 0; it < 5; ++it) {
    int nn = tid + it*512;
    if (nn < 2304) {
      int i2 = nn / 48, j2 = nn % 48;
      float4 v4 = *(const float4*)(vt + nn*8 + 4);
      float* cell = &Pp[((i2+1)*49 + (j2+1))*5];
      float e0 = ev[it];
      cell[0] = e0*v4.x; cell[1] = e0*v4.y; cell[2] = e0*v4.z; cell[3] = e0*v4.w;
    }
  }
  __syncthreads();
  if (tid < 192) {
    int j2 = tid >> 2, c = tid & 3; j2 += 1;
    float s = 0.f;
    for (int i0 = 1; i0 <= 48; i0 += 8) {
      float v[8];
      #pragma unroll
      for (int k = 0; k < 8; ++k) v[k] = Pp[((i0+k)*49 + j2)*5 + c];
      #pragma unroll
      for (int k = 0; k < 8; ++k) { s += v[k]; v[k] = s; }
      #pragma unroll
      for (int k = 0; k < 8; ++k) Pp[((i0+k)*49 + j2)*5 + c] = v[k];
    }
  }
  __syncthreads();
  if (tid < 192) {
    int i2 = tid >> 2, c = tid & 3; i2 += 1;
    float s = 0.f;
    for (int j0 = 1; j0 <= 48; j0 += 8) {
      float v[8];
      #pragma unroll
      for (int k = 0; k < 8; ++k) v[k] = Pp[(i2*49 + j0+k)*5 + c];
      #pragma unroll
      for (int k = 0; k < 8; ++k) { s += v[k]; v[k] = s; }
      #pragma unroll
      for (int k = 0; k < 8; ++k) Pp[(i2*49 + j0+k)*5 + c] = v[k];
    }
  }
  __syncthreads();
  {
    float* pb = ws + OFF_PB + (long)bh*9604;
    for (int idx = tid; idx < 9604; idx += 512) {
      int cell = idx >> 2, c = idx & 3;
      int ii = cell / 49, jj = cell % 49;
      pb[idx] = (ii && jj) ? Pp[cell*5 + c] : 0.f;
    }
  }
}

// ---------------- main fused kernel (MFMA, 2 heads/iter, 2 iters/phase) ----------------
// grid 9216 x 128 threads, 16 tokens/block, 2 waves. LDS 36864 B -> 4 blocks/CU.
// Double-buffered Tlds/CB: barriers per block drop 9 -> 5; each barrier
// interval holds 2 iterations of independent work (deeper ILP).
__global__ __launch_bounds__(128) void k_main(const float* __restrict__ ws,
                                              float* __restrict__ outp) {
  __shared__ __align__(16) unsigned short XNhi[16*64];
  __shared__ __align__(16) unsigned short XNlo[16*64];
  __shared__ __align__(16) unsigned short CBhi[2][16*128];
  __shared__ __align__(16) unsigned short CBlo[2][16*128];
  __shared__ __align__(16) float Tlds[2][16*128];

  int tid = threadIdx.x;
  int tok = tid >> 3, eg = tid & 7;       // 16 tok x 8 eg
  int lane = tid & 63, wv = tid >> 6;     // 2 waves
  int quad = lane >> 4, lrow = lane & 15;
  int wcol = wv;
  int bid = blockIdx.x;
  int bswz = (bid & 7) * 1152 + (bid >> 3);   // XCD-chunked, bijective on 9216
  long T0 = (long)bswz * 16;
  int b = (int)(T0 / 2304);
  int n = (int)(T0 % 2304) + tok;
  int i2 = n / 48, j2 = n % 48;

  // xn slice -> split -> LDS (swizzled)
  {
    const float4* p4 = (const float4*)(ws + OFF_XN + (T0 + tok)*64 + eg*8);
    float4 xa = p4[0], xb = p4[1];
    float xv[8] = {xa.x, xa.y, xa.z, xa.w, xb.x, xb.y, xb.z, xb.w};
    union { unsigned u[4]; uint2 d[2]; } ph, pl;
    #pragma unroll
    for (int k = 0; k < 8; k += 2) split2x2(xv[k], xv[k+1], ph.u[k>>1], pl.u[k>>1]);
    int off = tok*64 + ((eg*8) ^ ((tok & 7) << 3));
    *(uint2*)&XNhi[off]     = ph.d[0];
    *(uint2*)&XNhi[off + 4] = ph.d[1];
    *(uint2*)&XNlo[off]     = pl.d[0];
    *(uint2*)&XNlo[off + 4] = pl.d[1];
  }

  // phase0: cls slice in registers (source-head eg, channels eg*8..+8, 4 regions)
  float cls0[8], cls1[8], cls2[8], cls3[8];
  {
    float ec = ws[OFF_ECLS + b*8 + eg];
    const float* PA = ws + OFF_PA + (long)(b*8 + eg)*12005;
    const float* PB = ws + OFF_PB + (long)(b*8 + eg)*9604;
    int c_ij  = i2*49 + j2;
    int c_ij1 = c_ij + 1;
    int c_iW  = i2*49 + 48;
    int c_1j  = c_ij + 49;
    int c_1j1 = c_1j + 1;
    int c_1W  = c_iW + 49;
    int c_Hj  = 48*49 + j2;
    int c_Hj1 = c_Hj + 1;
    int c_HW  = 48*49 + 48;
    float rden[4];
    {
      float tl = PA[c_1j1*5];
      float tr = PA[c_1W*5] - PA[c_1j*5];
      float bl = PA[c_Hj1*5] - PA[c_ij1*5];
      float br = PA[c_HW*5] - PA[c_iW*5] - PA[c_Hj*5] + PA[c_ij*5];
      rden[0] = 1.0f/(ec + tl); rden[1] = 1.0f/(ec + tr);
      rden[2] = 1.0f/(ec + bl); rden[3] = 1.0f/(ec + br);
    }
    #pragma unroll
    for (int u = 0; u < 4; ++u) {
      int c = 1 + u;
      float tl = PA[c_1j1*5 + c];
      float tr = PA[c_1W*5 + c] - PA[c_1j*5 + c];
      float bl = PA[c_Hj1*5 + c] - PA[c_ij1*5 + c];
      float br = PA[c_HW*5 + c] - PA[c_iW*5 + c] - PA[c_Hj*5 + c] + PA[c_ij*5 + c];
      float nv = ec * ws[OFF_VC + eg*8 + u];
      cls0[u] = (nv + tl) * rden[0];
      cls1[u] = (nv + tr) * rden[1];
      cls2[u] = (nv + bl) * rden[2];
      cls3[u] = (nv + br) * rden[3];
    }
    #pragma unroll
    for (int u = 4; u < 8; ++u) {
      int c = u - 4;
      float tl = PB[c_1j1*4 + c];
      float tr = PB[c_1W*4 + c] - PB[c_1j*4 + c];
      float bl = PB[c_Hj1*4 + c] - PB[c_ij1*4 + c];
      float br = PB[c_HW*4 + c] - PB[c_iW*4 + c] - PB[c_Hj*4 + c] + PB[c_ij*4 + c];
      float nv = ec * ws[OFF_VC + eg*8 + u];
      cls0[u] = (nv + tl) * rden[0];
      cls1[u] = (nv + tr) * rden[1];
      cls2[u] = (nv + bl) * rden[2];
      cls3[u] = (nv + br) * rden[3];
    }
  }
  __syncthreads();

  const unsigned short* gball = (const unsigned short*)(ws + OFF_G);
  const unsigned short* zball = (const unsigned short*)(ws + OFF_Z);

  f32x4 oa0 = {0.f,0.f,0.f,0.f};
  f32x4 oa1 = {0.f,0.f,0.f,0.f};

  int rr = lrow;                      // A-operand row = token 0..15
  int sw3 = (rr & 7) << 3;
  const unsigned short* arh = XNhi + rr*64;
  const unsigned short* arl = XNlo + rr*64;

  for (int phs = 0; phs < 2; ++phs) {
    // ---- stage1 x2: T[sub][16x128] = XN @ [G_h0 | G_h1] (+v2) ----
    #pragma unroll
    for (int sub = 0; sub < 2; ++sub) {
      int h0 = (phs*2 + sub)*2;
      union { bf16x8 v; uint2 d[2]; } ah0, ah1, al0, al1;
      int oa = (quad*8) ^ sw3;
      int ob = (32 + quad*8) ^ sw3;
      ah0.d[0] = *(const uint2*)(arh + oa); ah0.d[1] = *(const uint2*)(arh + oa + 4);
      ah1.d[0] = *(const uint2*)(arh + ob); ah1.d[1] = *(const uint2*)(arh + ob + 4);
      al0.d[0] = *(const uint2*)(arl + oa); al0.d[1] = *(const uint2*)(arl + oa + 4);
      al1.d[0] = *(const uint2*)(arl + ob); al1.d[1] = *(const uint2*)(arl + ob + 4);
      #pragma unroll
      for (int c = 0; c < 4; ++c) {
        int colb = wcol*4 + c;                  // 0..7
        int e0 = colb*16 + lrow;                // 0..127
        const unsigned short* gh = gball + (h0 + (colb >> 2))*8192 + (colb & 3)*2048 + lane*8;
        bf16x8 bh0 = *(const bf16x8*)(gh);
        bf16x8 bl0 = *(const bf16x8*)(gh + 512);
        bf16x8 bh1 = *(const bf16x8*)(gh + 1024);
        bf16x8 bl1 = *(const bf16x8*)(gh + 1536);
        f32x4 acc = {0.f,0.f,0.f,0.f};
        __builtin_amdgcn_s_setprio(1);
        acc = __builtin_amdgcn_mfma_f32_16x16x32_bf16(ah0.v, bh0, acc, 0, 0, 0);
        acc = __builtin_amdgcn_mfma_f32_16x16x32_bf16(ah1.v, bh1, acc, 0, 0, 0);
        acc = __builtin_amdgcn_mfma_f32_16x16x32_bf16(al0.v, bh0, acc, 0, 0, 0);
        acc = __builtin_amdgcn_mfma_f32_16x16x32_bf16(al1.v, bh1, acc, 0, 0, 0);
        acc = __builtin_amdgcn_mfma_f32_16x16x32_bf16(ah0.v, bl0, acc, 0, 0, 0);
        acc = __builtin_amdgcn_mfma_f32_16x16x32_bf16(ah1.v, bl1, acc, 0, 0, 0);
        __builtin_amdgcn_s_setprio(0);
        float v2v = ws[OFF_V2 + h0*64 + e0];
        #pragma unroll
        for (int r = 0; r < 4; ++r) {
          int trow = quad*4 + r;               // 0..15
          Tlds[sub][trow*128 + (e0 ^ ((trow & 7) << 2))] = acc[r] + v2v;
        }
      }
    }
    __syncthreads();
    // ---- stage2 x2: scores -> softmax -> cbar -> split to CB[sub] ----
    #pragma unroll
    for (int sub = 0; sub < 2; ++sub) {
      float tv0[8], tv1[8];
      {
        int base = tok*128;
        int sw2 = (tok & 7) << 2;
        float4 a0 = *(const float4*)&Tlds[sub][base + ((eg*8) ^ sw2)];
        float4 b0 = *(const float4*)&Tlds[sub][base + ((eg*8 + 4) ^ sw2)];
        float4 a1 = *(const float4*)&Tlds[sub][base + ((64 + eg*8) ^ sw2)];
        float4 b1 = *(const float4*)&Tlds[sub][base + ((64 + eg*8 + 4) ^ sw2)];
        tv0[0]=a0.x; tv0[1]=a0.y; tv0[2]=a0.z; tv0[3]=a0.w;
        tv0[4]=b0.x; tv0[5]=b0.y; tv0[6]=b0.z; tv0[7]=b0.w;
        tv1[0]=a1.x; tv1[1]=a1.y; tv1[2]=a1.z; tv1[3]=a1.w;
        tv1[4]=b1.x; tv1[5]=b1.y; tv1[6]=b1.z; tv1[7]=b1.w;
      }
      float p0=0.f,p1=0.f,p2=0.f,p3=0.f,q0=0.f,q1=0.f,q2=0.f,q3=0.f;
      #pragma unroll
      for (int k = 0; k < 8; ++k) {
        p0 += tv0[k]*cls0[k]; p1 += tv0[k]*cls1[k];
        p2 += tv0[k]*cls2[k]; p3 += tv0[k]*cls3[k];
        q0 += tv1[k]*cls0[k]; q1 += tv1[k]*cls1[k];
        q2 += tv1[k]*cls2[k]; q3 += tv1[k]*cls3[k];
      }
      #pragma unroll
      for (int mk = 1; mk < 8; mk <<= 1) {
        p0 += __shfl_xor(p0, mk, 8); p1 += __shfl_xor(p1, mk, 8);
        p2 += __shfl_xor(p2, mk, 8); p3 += __shfl_xor(p3, mk, 8);
        q0 += __shfl_xor(q0, mk, 8); q1 += __shfl_xor(q1, mk, 8);
        q2 += __shfl_xor(q2, mk, 8); q3 += __shfl_xor(q3, mk, 8);
      }
      union { unsigned u[4]; uint2 d[2]; } ch, cl;
      int cbBase = tok*128;
      int swc = (tok & 7) << 3;
      {
        float s0 = p0*SCALE_RA, s1 = p1*SCALE_RA, s2 = p2*SCALE_RA, s3 = p3*SCALE_RA;
        float mm = fmaxf(fmaxf(s0, s1), fmaxf(s2, s3));
        float e0 = __expf(s0-mm), e1 = __expf(s1-mm), e2 = __expf(s2-mm), e3 = __expf(s3-mm);
        float inv = 1.0f/(e0+e1+e2+e3);
        float av0 = e0*inv, av1 = e1*inv, av2 = e2*inv, av3 = e3*inv;
        #pragma unroll
        for (int k = 0; k < 8; k += 2) {
          float cv0 = av0*cls0[k] + av1*cls1[k] + av2*cls2[k] + av3*cls3[k];
          float cv1 = av0*cls0[k+1] + av1*cls1[k+1] + av2*cls2[k+1] + av3*cls3[k+1];
          split2x2(cv0, cv1, ch.u[k>>1], cl.u[k>>1]);
        }
        int o = cbBase + ((eg*8) ^ swc);
        *(uint2*)&CBhi[sub][o]     = ch.d[0]; *(uint2*)&CBhi[sub][o + 4] = ch.d[1];
        *(uint2*)&CBlo[sub][o]     = cl.d[0]; *(uint2*)&CBlo[sub][o + 4] = cl.d[1];
      }
      {
        float s0 = q0*SCALE_RA, s1 = q1*SCALE_RA, s2 = q2*SCALE_RA, s3 = q3*SCALE_RA;
        float mm = fmaxf(fmaxf(s0, s1), fmaxf(s2, s3));
        float e0 = __expf(s0-mm), e1 = __expf(s1-mm), e2 = __expf(s2-mm), e3 = __expf(s3-mm);
        float inv = 1.0f/(e0+e1+e2+e3);
        float av0 = e0*inv, av1 = e1*inv, av2 = e2*inv, av3 = e3*inv;
        #pragma unroll
        for (int k = 0; k < 8; k += 2) {
          float cv0 = av0*cls0[k] + av1*cls1[k] + av2*cls2[k] + av3*cls3[k];
          float cv1 = av0*cls0[k+1] + av1*cls1[k+1] + av2*cls2[k+1] + av3*cls3[k+1];
          split2x2(cv0, cv1, ch.u[k>>1], cl.u[k>>1]);
        }
        int o = cbBase + ((64 + eg*8) ^ swc);
        *(uint2*)&CBhi[sub][o]     = ch.d[0]; *(uint2*)&CBhi[sub][o + 4] = ch.d[1];
        *(uint2*)&CBlo[sub][o]     = cl.d[0]; *(uint2*)&CBlo[sub][o + 4] = cl.d[1];
      }
    }
    __syncthreads();
    // ---- stage3 x2: OUT(16x64) += CB[sub](16x128) @ [Zt_h0 ; Zt_h1] ----
    #pragma unroll
    for (int sub = 0; sub < 2; ++sub) {
      int h0 = (phs*2 + sub)*2;
      const unsigned short* crh = &CBhi[sub][rr*128];
      const unsigned short* crl = &CBlo[sub][rr*128];
      #pragma unroll
      for (int c = 0; c < 2; ++c) {
        int colb = wcol*2 + c;                  // 0..3
        int e0 = colb*16 + lrow;                // 0..63
        f32x4 acc = (c == 0) ? oa0 : oa1;
        #pragma unroll
        for (int kb = 0; kb < 4; ++kb) {
          union { bf16x8 v; uint2 d[2]; } ah, al;
          int o = (kb*32 + quad*8) ^ sw3;
          ah.d[0] = *(const uint2*)(crh + o); ah.d[1] = *(const uint2*)(crh + o + 4);
          al.d[0] = *(const uint2*)(crl + o); al.d[1] = *(const uint2*)(crl + o + 4);
          const unsigned short* zc = zball + (h0 + (kb >> 1))*8192 + colb*2048 + (kb & 1)*1024 + lane*8;
          bf16x8 bh = *(const bf16x8*)(zc);
          bf16x8 bl = *(const bf16x8*)(zc + 512);
          __builtin_amdgcn_s_setprio(1);
          acc = __builtin_amdgcn_mfma_f32_16x16x32_bf16(ah.v, bh, acc, 0, 0, 0);
          acc = __builtin_amdgcn_mfma_f32_16x16x32_bf16(al.v, bh, acc, 0, 0, 0);
          acc = __builtin_amdgcn_mfma_f32_16x16x32_bf16(ah.v, bl, acc, 0, 0, 0);
          __builtin_amdgcn_s_setprio(0);
        }
        if (c == 0) oa0 = acc; else oa1 = acc;
      }
    }
  }
  // epilogue
  #pragma unroll
  for (int c = 0; c < 2; ++c) {
    int e0 = (wcol*2 + c)*16 + lrow;
    float cov = ws[OFF_C1 + e0];
    f32x4 oa = (c == 0) ? oa0 : oa1;
    #pragma unroll
    for (int r = 0; r < 4; ++r)
      outp[(T0 + quad*4 + r)*64 + e0] = oa[r] + cov;
  }
}

extern "C" void kernel_launch(void* const* d_in, const int* in_sizes, int n_in,
                              void* d_out, int out_size, void* d_ws, size_t ws_size,
                              hipStream_t stream) {
  const float* x      = (const float*)d_in[0];
  const float* ln_g   = (const float*)d_in[1];
  const float* ln_b   = (const float*)d_in[2];
  const float* Wqkv   = (const float*)d_in[3];
  const float* bqkv   = (const float*)d_in[4];
  const float* cls_tok= (const float*)d_in[5];
  const float* Wwqkv  = (const float*)d_in[6];
  const float* bwqkv  = (const float*)d_in[7];
  const float* Wwproj = (const float*)d_in[8];
  const float* bwproj = (const float*)d_in[9];
  const float* Wraq   = (const float*)d_in[10];
  const float* Wrak   = (const float*)d_in[11];
  const float* Wrav   = (const float*)d_in[12];
  const float* Wrao   = (const float*)d_in[13];
  const float* brao   = (const float*)d_in[14];
  const float* Wout   = (const float*)d_in[15];
  const float* bout   = (const float*)d_in[16];
  float* ws = (float*)d_ws;
  float* outp = (float*)d_out;

  hipLaunchKernelGGL(k_pre, dim3(2321), dim3(256), 0, stream,
                     x, ln_g, ln_b, Wqkv, bqkv, cls_tok, Wwqkv, bwqkv,
                     Wwproj, bwproj, Wraq, Wrak, Wrav, Wrao, brao, Wout, bout, ws);
  hipLaunchKernelGGL(k_prefix, dim3(512), dim3(512), 0, stream, ws);
  hipLaunchKernelGGL(k_main, dim3(9216), dim3(128), 0, stream, ws, outp);
}

// Round 14
// 327.191 us; speedup vs baseline: 1.0596x; 1.0596x over previous
//
#include <hip/hip_runtime.h>
#include <math.h>

// FourRegionAttention on MI355X (gfx950). B=64, n=2304 (48x48), D=64, h=8, hd=8.
// 3-kernel pipeline: k_pre (fused setup1+setupW+lnkv; setup blocks FIRST;
// KT/VT staged through XOR-swizzled LDS for coalesced stores) -> k_prefix
// (512 blocks, one per bh) -> k_main (16-tok blocks, fragment-swizzled G/Z;
// XCD-chunked blockIdx swizzle [FETCH 94->41MB, r12] + s_setprio).
// r13's 2-iters/phase double-buffer REGRESSED (156->173us: LDS 36.9KB cost
// 3 blocks/CU of load-bearing TLP) -> reverted to r12 single-buffer form.
// k_main A-fragments re-read from LDS per iteration (r7 hoist regressed).
// NOTE: no min-waves arg on __launch_bounds__ (spill hazard, r1-r2).

#define SCALE_W  0.3535533905932738f   // 8^-0.5
#define SCALE_RA 0.3535533905932738f
#define LN_EPS 1e-5f

typedef __attribute__((ext_vector_type(8))) short bf16x8;
typedef __attribute__((ext_vector_type(4))) float f32x4;

// ---- workspace layout (float offsets) ----
#define OFF_XN   0ull
#define SZ_XN    (64ull*2304*64)            // 9437184
#define OFF_KT   (OFF_XN + SZ_XN)           // k_t [b][h][n][8]
#define SZ_KT    (64ull*8*2304*8)           // 9437184
#define OFF_VT   (OFF_KT + SZ_KT)           // v_t [b][h][n][8]
#define OFF_PA   (OFF_VT + SZ_KT)           // PA [bh][2401][5]: e, e*v[0..3] prefix
#define SZ_PA    (512ull*2401*5)
#define OFF_PB   (OFF_PA + SZ_PA)           // PB [bh][2401][4]: e*v[4..7] prefix
#define SZ_PB    (512ull*2401*4)
#define OFF_ECLS (OFF_PB + SZ_PB)           // 512
#define OFF_QC   (OFF_ECLS + 512)           // 64 (scaled q_c)
#define OFF_KC   (OFF_QC + 64)              // 64
#define OFF_VC   (OFF_KC + 64)              // 64
#define OFF_CLOG (OFF_VC + 64)              // 8
#define OFF_BK   (OFF_CLOG + 8)             // 64  (dead - kept for layout)
#define OFF_BV   (OFF_BK + 64)              // 64
#define OFF_AH   (OFF_BV + 64)              // 512 a_h = Wraq@bqkv_h
#define OFF_W1   (OFF_AH + 512)             // 64  (dead - kept for layout)
#define OFF_WZ   (OFF_W1 + 64)              // 64  Wrao@bv
#define OFF_B2   (OFF_WZ + 64)              // 512 Wrak^T@a_h
#define OFF_V2   (OFF_B2 + 512)             // 512 v2_h
#define OFF_UH   (OFF_V2 + 512)             // 512 (dead - kept for layout)
#define OFF_CH   (OFF_UH + 512)             // 8   (dead - kept for layout)
#define OFF_C1   (OFF_CH + 8)               // 64  const output bias
// GB/ZB: per head 8192 ushorts = 16 records x 512 ushorts (1KB each).
// record idx within head: tile(e>>4)*2048 + half(d>>5)*1024 + plane*512,
// entry: lane = ((d>>3)&3)*16 + (e&15), j = d&7  (fragment lane-major).
#define OFF_G    (OFF_C1 + 64)              // 32768 floats
#define OFF_Z    (OFF_G + 32768)            // 32768 floats

__device__ inline void split2(float x, unsigned short &h, unsigned short &l) {
  unsigned u = __float_as_uint(x);
  unsigned hr = (u + 0x7fffu + ((u >> 16) & 1u)) >> 16;
  h = (unsigned short)hr;
  float hf = __uint_as_float(hr << 16);
  float lo = x - hf;
  unsigned u2 = __float_as_uint(lo);
  l = (unsigned short)((u2 + 0x7fffu + ((u2 >> 16) & 1u)) >> 16);
}

// split a pair of floats into packed bf16 hi words + packed bf16 lo-residual
// words using the HW packed converter (RNE, same rounding as split2).
__device__ inline void split2x2(float x0, float x1, unsigned &h, unsigned &l) {
  asm("v_cvt_pk_bf16_f32 %0, %1, %2" : "=v"(h) : "v"(x0), "v"(x1));
  float r0 = x0 - __uint_as_float(h << 16);
  float r1 = x1 - __uint_as_float(h & 0xffff0000u);
  asm("v_cvt_pk_bf16_f32 %0, %1, %2" : "=v"(l) : "v"(r0), "v"(r1));
}

__device__ inline float dot64(const float* __restrict__ a, const float* __restrict__ b) {
  float s0 = 0.f, s1 = 0.f, s2 = 0.f, s3 = 0.f;
  #pragma unroll
  for (int d = 0; d < 64; d += 4) {
    float4 av = *(const float4*)(a + d);
    float4 bv = *(const float4*)(b + d);
    s0 += av.x * bv.x; s1 += av.y * bv.y;
    s2 += av.z * bv.z; s3 += av.w * bv.w;
  }
  return (s0 + s1) + (s2 + s3);
}

// ---------------- fused pre-kernel: setup1 (blk 0) | setupW (1..16) | lnkv (17..2320) ----------------
__global__ __launch_bounds__(256) void k_pre(const float* __restrict__ x,
      const float* __restrict__ ln_g, const float* __restrict__ ln_b,
      const float* __restrict__ Wqkv, const float* __restrict__ bqkv,
      const float* __restrict__ cls_tok, const float* __restrict__ Wwqkv,
      const float* __restrict__ bwqkv, const float* __restrict__ Wwproj,
      const float* __restrict__ bwproj, const float* __restrict__ Wraq,
      const float* __restrict__ Wrak, const float* __restrict__ Wrav,
      const float* __restrict__ Wrao, const float* __restrict__ brao,
      const float* __restrict__ Wout, const float* __restrict__ bout,
      float* __restrict__ ws) {
  __shared__ float smu[12928];   // union: lnkv 12928 | setupW 8320 | setup1 64 | kv-stage 8192
  int tid = threadIdx.x;
  int blk = blockIdx.x;

  if (blk >= 17) {
    // ======== LayerNorm + k/v GEMM ========
    float* xnT = smu;                 // [d][68]
    float* xt  = smu + 4352;          // [tok][65]
    float* wkv = smu + 4352;          // [d][132]
    float* muL = smu + 4352 + 8448;
    float* rsL = muL + 64;

    long T0 = (long)(blk - 17) * 64;
    int tok = tid >> 2, seg = tid & 3;

    const float4* x4 = (const float4*)(x + (T0 + tok)*64 + seg*16);
    float4 va = x4[0], vb = x4[1], vc4 = x4[2], vd = x4[3];
    {
      float* xp = xt + tok*65 + seg*16;
      xp[0]=va.x; xp[1]=va.y; xp[2]=va.z; xp[3]=va.w;
      xp[4]=vb.x; xp[5]=vb.y; xp[6]=vb.z; xp[7]=vb.w;
      xp[8]=vc4.x; xp[9]=vc4.y; xp[10]=vc4.z; xp[11]=vc4.w;
      xp[12]=vd.x; xp[13]=vd.y; xp[14]=vd.z; xp[15]=vd.w;
    }
    __syncthreads();
    if (tid < 64) {
      float s = 0.f;
      for (int i2 = 0; i2 < 64; ++i2) s += xt[tid*65 + i2];
      float mu = s * (1.0f/64.0f);
      float v = 0.f;
      for (int i2 = 0; i2 < 64; ++i2) { float d = xt[tid*65 + i2] - mu; v += d*d; }
      v *= (1.0f/64.0f);
      muL[tid] = mu; rsL[tid] = 1.0f / sqrtf(v + LN_EPS);
    }
    __syncthreads();
    {
      float mu = muL[tok], rs = rsL[tok];
      float xv[16];
      #pragma unroll
      for (int k = 0; k < 16; ++k) {
        int i2 = seg*16 + k;
        float v = (xt[tok*65 + i2] - mu) * rs * ln_g[i2] + ln_b[i2];
        xv[k] = v;
        xnT[i2*68 + tok] = v;
      }
      float4* xng = (float4*)(ws + OFF_XN + (T0 + tok)*64 + seg*16);
      xng[0] = make_float4(xv[0], xv[1], xv[2], xv[3]);
      xng[1] = make_float4(xv[4], xv[5], xv[6], xv[7]);
      xng[2] = make_float4(xv[8], xv[9], xv[10], xv[11]);
      xng[3] = make_float4(xv[12], xv[13], xv[14], xv[15]);
    }
    __syncthreads();
    {
      int o = tid >> 1, dh = (tid & 1) * 32;
      #pragma unroll
      for (int k = 0; k < 32; k += 4) {
        float4 w4 = *(const float4*)(Wwqkv + (64 + o)*64 + dh + k);
        wkv[(dh+k+0)*132 + o] = w4.x;
        wkv[(dh+k+1)*132 + o] = w4.y;
        wkv[(dh+k+2)*132 + o] = w4.z;
        wkv[(dh+k+3)*132 + o] = w4.w;
      }
    }
    __syncthreads();
    int tokq = tid & 15, og = tid >> 4;
    float acc[4][8];
    #pragma unroll
    for (int ti = 0; ti < 4; ++ti)
      #pragma unroll
      for (int k = 0; k < 8; ++k) acc[ti][k] = 0.f;
    for (int d2 = 0; d2 < 64; ++d2) {
      float4 a4 = *(float4*)&xnT[d2*68 + tokq*4];
      float4 b0 = *(float4*)&wkv[d2*132 + og*8];
      float4 b1 = *(float4*)&wkv[d2*132 + og*8 + 4];
      float aa[4] = {a4.x, a4.y, a4.z, a4.w};
      float bbv[8] = {b0.x,b0.y,b0.z,b0.w,b1.x,b1.y,b1.z,b1.w};
      #pragma unroll
      for (int ti = 0; ti < 4; ++ti)
        #pragma unroll
        for (int k = 0; k < 8; ++k) acc[ti][k] += aa[ti]*bbv[k];
    }
    float bsv[8];
    #pragma unroll
    for (int k = 0; k < 8; ++k) bsv[k] = bwqkv[64 + og*8 + k];
    // ---- stage into XOR-swizzled LDS, then fully-coalesced global stores ----
    __syncthreads();                       // all xnT/wkv reads done
    float4* kvb = (float4*)smu;            // 2048 float4 = 8192 floats
    #pragma unroll
    for (int ti = 0; ti < 4; ++ti) {
      int ntok = tokq*4 + ti;
      int L0 = og*128 + ntok*2;
      int p0 = L0 ^ ((L0 >> 3) & 7);
      int p1 = (L0 + 1) ^ (((L0 + 1) >> 3) & 7);
      kvb[p0] = make_float4(acc[ti][0]+bsv[0], acc[ti][1]+bsv[1], acc[ti][2]+bsv[2], acc[ti][3]+bsv[3]);
      kvb[p1] = make_float4(acc[ti][4]+bsv[4], acc[ti][5]+bsv[5], acc[ti][6]+bsv[6], acc[ti][7]+bsv[7]);
    }
    __syncthreads();
    int bb = (int)(T0 / 2304);
    int nlbase = (int)(T0 % 2304);
    #pragma unroll
    for (int r = 0; r < 8; ++r) {
      int L = tid + r*256;
      int ogr = L >> 7;
      int hhr = ogr & 7;
      int ntok = (L >> 1) & 63;
      int cc = L & 1;
      int phys = L ^ ((L >> 3) & 7);
      float4 val = kvb[phys];
      unsigned long long dstoff = (ogr < 8) ? OFF_KT : OFF_VT;
      float* dst = ws + dstoff + ((long)(bb*8 + hhr)*2304 + (nlbase + ntok))*8 + cc*4;
      *(float4*)dst = val;
    }
  } else if (blk >= 1) {
    // ======== per-head G/Z chains -> fragment-swizzled bf16 ========
    float* A  = smu;
    float* Bl = smu + 4160;
    int wblk = blk - 1;
    if (wblk < 8) {
      int hh = wblk;
      for (int o = tid; o < 4096; o += 256) {
        int d = o & 63, e = o >> 6; float s = 0.f;
        for (int f = 0; f < 64; ++f) s += Wraq[f*64+d] * Wrak[f*64+e];
        A[d*65 + e] = s;
      }
      __syncthreads();
      for (int o = tid; o < 4096; o += 256) {
        int j = o & 63, i = o >> 6; float s = 0.f;
        for (int f = 0; f < 64; ++f) s += A[i*65 + f] * Wwproj[f*64 + j];
        Bl[i*65 + j] = s;
      }
      __syncthreads();
      unsigned short* gb = (unsigned short*)(ws + OFF_G) + hh*8192;
      for (int o = tid; o < 4096; o += 256) {
        int d = o & 63, e = o >> 6; float s = 0.f;
        for (int f = 0; f < 64; ++f) s += Wqkv[(hh*64+f)*64 + d] * Bl[f*65 + e];
        unsigned short h16, l16;
        split2(s, h16, l16);
        int base = (e >> 4)*2048 + (d >> 5)*1024 + (((d >> 3) & 3)*16 + (e & 15))*8 + (d & 7);
        gb[base]       = h16;   // plane hi
        gb[base + 512] = l16;   // plane lo
      }
    } else {
      int hh = wblk - 8;
      for (int o = tid; o < 4096; o += 256) {
        int d = o & 63, e = o >> 6; float s = 0.f;
        for (int f = 0; f < 64; ++f) s += Wrav[e*64+f] * Wwproj[f*64+d];
        A[e*65 + d] = s;
      }
      __syncthreads();
      for (int o = tid; o < 4096; o += 256) {
        int d = o & 63, i = o >> 6; float s = 0.f;
        for (int f = 0; f < 64; ++f) s += Wrao[i*64+f] * A[f*65 + d];
        Bl[i*65 + d] = s;
      }
      __syncthreads();
      unsigned short* zb = (unsigned short*)(ws + OFF_Z) + hh*8192;
      for (int o = tid; o < 4096; o += 256) {
        int d = o & 63, e = o >> 6; float s = 0.f;  // d = channel, e = out-dim
        for (int f = 0; f < 64; ++f) s += Wout[e*512 + hh*64 + f] * Bl[f*65 + d];
        unsigned short h16, l16;
        split2(s, h16, l16);
        int base = (e >> 4)*2048 + (d >> 5)*1024 + (((d >> 3) & 3)*16 + (e & 15))*8 + (d & 7);
        zb[base]       = h16;
        zb[base + 512] = l16;
      }
    }
  } else {
    // ======== small folded vectors (single block) ========
    float* bwz = smu;
    for (int idx = tid; idx < 768; idx += 256) {
      if (idx < 192) {
        float s = bwqkv[idx] + dot64(Wwqkv + idx*64, cls_tok);
        if (idx < 64) ws[OFF_QC + idx] = s * SCALE_W;
        else if (idx < 128) ws[OFF_KC + idx - 64] = s;
        else ws[OFF_VC + idx - 128] = s;
      } else if (idx < 256) {
        int e = idx - 192;
        ws[OFF_BV + e] = dot64(Wrav + e*64, bwproj);
      } else {
        int t2 = idx - 256; int hh = t2 >> 6, e = t2 & 63;
        ws[OFF_AH + t2] = dot64(Wraq + e*64, bqkv + hh*64);
      }
    }
    __syncthreads();
    for (int idx = tid; idx < 584; idx += 256) {
      if (idx < 8) {
        float s = 0.f;
        for (int u = 0; u < 8; ++u) s += ws[OFF_QC + idx*8+u] * ws[OFF_KC + idx*8+u];
        ws[OFF_CLOG + idx] = s;
      } else if (idx < 72) {
        int e = idx - 8;
        ws[OFF_WZ + e] = dot64(Wrao + e*64, ws + OFF_BV);
      } else {
        int t2 = idx - 72; int hh = t2 >> 6, e = t2 & 63; float s = 0.f;
        for (int d = 0; d < 64; ++d) s += Wrak[d*64+e] * ws[OFF_AH + hh*64+d];
        ws[OFF_B2 + t2] = s;
      }
    }
    __syncthreads();
    if (tid < 64) bwz[tid] = brao[tid] + ws[OFF_WZ + tid];
    __syncthreads();
    for (int idx = tid; idx < 576; idx += 256) {
      if (idx < 512) {
        int hh = idx >> 6, e = idx & 63; float s = 0.f;
        for (int d = 0; d < 64; ++d) s += Wwproj[d*64+e] * ws[OFF_B2 + hh*64+d];
        ws[OFF_V2 + idx] = s;
      } else {
        int e = idx - 512;
        float s0 = 0.f, s1 = 0.f, s2 = 0.f, s3 = 0.f;
        for (int f = 0; f < 512; f += 4) {
          float4 w4 = *(const float4*)(Wout + e*512 + f);
          float4 b4 = *(const float4*)&bwz[f & 63];
          s0 += w4.x*b4.x; s1 += w4.y*b4.y; s2 += w4.z*b4.z; s3 += w4.w*b4.w;
        }
        ws[OFF_C1 + e] = bout[e] + (s0 + s1) + (s2 + s3);
      }
    }
  }
}

// ---------------- logits + softmax-normalizer + 2D prefix sums ----------------
__global__ __launch_bounds__(512) void k_prefix(float* __restrict__ ws) {
  __shared__ float Pp[49*49*5];
  __shared__ float red[8];
  int tid = threadIdx.x;
  int bh = blockIdx.x;
  int hh = bh & 7;
  const float* kt = ws + OFF_KT + (long)bh*2304*8;
  const float* vt = ws + OFF_VT + (long)bh*2304*8;
  float qc[8];
  #pragma unroll
  for (int u = 0; u < 8; ++u) qc[u] = ws[OFF_QC + hh*8 + u];
  float ev[5];
  float mloc = -1e30f;
  #pragma unroll
  for (int it = 0; it < 5; ++it) {
    int nn = tid + it*512;
    if (nn < 2304) {
      const float4* kk = (const float4*)(kt + nn*8);
      float4 k0 = kk[0], k1 = kk[1];
      float lv = qc[0]*k0.x + qc[1]*k0.y + qc[2]*k0.z + qc[3]*k0.w
               + qc[4]*k1.x + qc[5]*k1.y + qc[6]*k1.z + qc[7]*k1.w;
      ev[it] = lv;
      mloc = fmaxf(mloc, lv);
    }
  }
  #pragma unroll
  for (int mk = 1; mk < 64; mk <<= 1) mloc = fmaxf(mloc, __shfl_xor(mloc, mk, 64));
  if ((tid & 63) == 0) red[tid >> 6] = mloc;
  __syncthreads();
  float m = fmaxf(fmaxf(fmaxf(red[0], red[1]), fmaxf(red[2], red[3])),
                  fmaxf(fmaxf(red[4], red[5]), fmaxf(red[6], red[7])));
  m = fmaxf(m, ws[OFF_CLOG + hh]);
  if (tid == 0) ws[OFF_ECLS + bh] = __expf(ws[OFF_CLOG + hh] - m);
  #pragma unroll
  for (int it = 0; it < 5; ++it) {
    int nn = tid + it*512;
    if (nn < 2304) ev[it] = __expf(ev[it] - m);
  }
  // ---- pass A: columns [e, e*v0..3] ----
  #pragma unroll
  for (int it = 0; it < 5; ++it) {
    int nn = tid + it*512;
    if (nn < 2304) {
      int i2 = nn / 48, j2 = nn % 48;
      float4 v4 = *(const float4*)(vt + nn*8);
      float* cell = &Pp[((i2+1)*49 + (j2+1))*5];
      float e0 = ev[it];
      cell[0] = e0; cell[1] = e0*v4.x; cell[2] = e0*v4.y; cell[3] = e0*v4.z; cell[4] = e0*v4.w;
    }
  }
  __syncthreads();
  if (tid < 240) {
    int j2 = tid / 5 + 1, c = tid % 5;
    float s = 0.f;
    for (int i0 = 1; i0 <= 48; i0 += 8) {
      float v[8];
      #pragma unroll
      for (int k = 0; k < 8; ++k) v[k] = Pp[((i0+k)*49 + j2)*5 + c];
      #pragma unroll
      for (int k = 0; k < 8; ++k) { s += v[k]; v[k] = s; }
      #pragma unroll
      for (int k = 0; k < 8; ++k) Pp[((i0+k)*49 + j2)*5 + c] = v[k];
    }
  }
  __syncthreads();
  if (tid < 240) {
    int i2 = tid / 5 + 1, c = tid % 5;
    float s = 0.f;
    for (int j0 = 1; j0 <= 48; j0 += 8) {
      float v[8];
      #pragma unroll
      for (int k = 0; k < 8; ++k) v[k] = Pp[(i2*49 + j0+k)*5 + c];
      #pragma unroll
      for (int k = 0; k < 8; ++k) { s += v[k]; v[k] = s; }
      #pragma unroll
      for (int k = 0; k < 8; ++k) Pp[(i2*49 + j0+k)*5 + c] = v[k];
    }
  }
  __syncthreads();
  {
    float* pa = ws + OFF_PA + (long)bh*12005;
    for (int idx = tid; idx < 12005; idx += 512) {
      int cell = idx / 5;
      int ii = cell / 49, jj = cell % 49;
      pa[idx] = (ii && jj) ? Pp[idx] : 0.f;
    }
  }
  __syncthreads();
  // ---- pass B: columns [e*v4..7] (stride-5 layout, 4 used) ----
  #pragma unroll
  for (int it = 0; it < 5; ++it) {
    int nn = tid + it*512;
    if (nn < 2304) {
      int i2 = nn / 48, j2 = nn % 48;
      float4 v4 = *(const float4*)(vt + nn*8 + 4);
      float* cell = &Pp[((i2+1)*49 + (j2+1))*5];
      float e0 = ev[it];
      cell[0] = e0*v4.x; cell[1] = e0*v4.y; cell[2] = e0*v4.z; cell[3] = e0*v4.w;
    }
  }
  __syncthreads();
  if (tid < 192) {
    int j2 = tid >> 2, c = tid & 3; j2 += 1;
    float s = 0.f;
    for (int i0 = 1; i0 <= 48; i0 += 8) {
      float v[8];
      #pragma unroll
      for (int k = 0; k < 8; ++k) v[k] = Pp[((i0+k)*49 + j2)*5 + c];
      #pragma unroll
      for (int k = 0; k < 8; ++k) { s += v[k]; v[k] = s; }
      #pragma unroll
      for (int k = 0; k < 8; ++k) Pp[((i0+k)*49 + j2)*5 + c] = v[k];
    }
  }
  __syncthreads();
  if (tid < 192) {
    int i2 = tid >> 2, c = tid & 3; i2 += 1;
    float s = 0.f;
    for (int j0 = 1; j0 <= 48; j0 += 8) {
      float v[8];
      #pragma unroll
      for (int k = 0; k < 8; ++k) v[k] = Pp[(i2*49 + j0+k)*5 + c];
      #pragma unroll
      for (int k = 0; k < 8; ++k) { s += v[k]; v[k] = s; }
      #pragma unroll
      for (int k = 0; k < 8; ++k) Pp[(i2*49 + j0+k)*5 + c] = v[k];
    }
  }
  __syncthreads();
  {
    float* pb = ws + OFF_PB + (long)bh*9604;
    for (int idx = tid; idx < 9604; idx += 512) {
      int cell = idx >> 2, c = idx & 3;
      int ii = cell / 49, jj = cell % 49;
      pb[idx] = (ii && jj) ? Pp[cell*5 + c] : 0.f;
    }
  }
}

// ---------------- main fused kernel (MFMA, 2 heads/iter) ----------------
// grid 9216 x 128 threads, 16 tokens/block, 2 waves. LDS 20480 B.
// XCD-chunked blockIdx swizzle (9216%8==0, bijective): each XCD gets a
// contiguous 1152-block run = 8 batches -> PA/PB panels L2-resident.
// G/Z fragment loads: base + lane*16B -> one coalesced dwordx4 per fragment.
// A-fragments re-read from LDS per iteration (free; hides G-load latency).
__global__ __launch_bounds__(128) void k_main(const float* __restrict__ ws,
                                              float* __restrict__ outp) {
  __shared__ __align__(16) unsigned short XNhi[16*64];
  __shared__ __align__(16) unsigned short XNlo[16*64];
  __shared__ __align__(16) unsigned short CBhi[16*128];
  __shared__ __align__(16) unsigned short CBlo[16*128];
  __shared__ __align__(16) float Tlds[16*128];

  int tid = threadIdx.x;
  int tok = tid >> 3, eg = tid & 7;       // 16 tok x 8 eg
  int lane = tid & 63, wv = tid >> 6;     // 2 waves
  int quad = lane >> 4, lrow = lane & 15;
  int wcol = wv;
  int bid = blockIdx.x;
  int bswz = (bid & 7) * 1152 + (bid >> 3);   // XCD-chunked, bijective on 9216
  long T0 = (long)bswz * 16;
  int b = (int)(T0 / 2304);
  int n = (int)(T0 % 2304) + tok;
  int i2 = n / 48, j2 = n % 48;

  // xn slice -> split -> LDS (swizzled)
  {
    const float4* p4 = (const float4*)(ws + OFF_XN + (T0 + tok)*64 + eg*8);
    float4 xa = p4[0], xb = p4[1];
    float xv[8] = {xa.x, xa.y, xa.z, xa.w, xb.x, xb.y, xb.z, xb.w};
    union { unsigned u[4]; uint2 d[2]; } ph, pl;
    #pragma unroll
    for (int k = 0; k < 8; k += 2) split2x2(xv[k], xv[k+1], ph.u[k>>1], pl.u[k>>1]);
    int off = tok*64 + ((eg*8) ^ ((tok & 7) << 3));
    *(uint2*)&XNhi[off]     = ph.d[0];
    *(uint2*)&XNhi[off + 4] = ph.d[1];
    *(uint2*)&XNlo[off]     = pl.d[0];
    *(uint2*)&XNlo[off + 4] = pl.d[1];
  }

  // phase0: cls slice in registers (source-head eg, channels eg*8..+8, 4 regions)
  float cls0[8], cls1[8], cls2[8], cls3[8];
  {
    float ec = ws[OFF_ECLS + b*8 + eg];
    const float* PA = ws + OFF_PA + (long)(b*8 + eg)*12005;
    const float* PB = ws + OFF_PB + (long)(b*8 + eg)*9604;
    int c_ij  = i2*49 + j2;
    int c_ij1 = c_ij + 1;
    int c_iW  = i2*49 + 48;
    int c_1j  = c_ij + 49;
    int c_1j1 = c_1j + 1;
    int c_1W  = c_iW + 49;
    int c_Hj  = 48*49 + j2;
    int c_Hj1 = c_Hj + 1;
    int c_HW  = 48*49 + 48;
    float rden[4];
    {
      float tl = PA[c_1j1*5];
      float tr = PA[c_1W*5] - PA[c_1j*5];
      float bl = PA[c_Hj1*5] - PA[c_ij1*5];
      float br = PA[c_HW*5] - PA[c_iW*5] - PA[c_Hj*5] + PA[c_ij*5];
      rden[0] = 1.0f/(ec + tl); rden[1] = 1.0f/(ec + tr);
      rden[2] = 1.0f/(ec + bl); rden[3] = 1.0f/(ec + br);
    }
    #pragma unroll
    for (int u = 0; u < 4; ++u) {
      int c = 1 + u;
      float tl = PA[c_1j1*5 + c];
      float tr = PA[c_1W*5 + c] - PA[c_1j*5 + c];
      float bl = PA[c_Hj1*5 + c] - PA[c_ij1*5 + c];
      float br = PA[c_HW*5 + c] - PA[c_iW*5 + c] - PA[c_Hj*5 + c] + PA[c_ij*5 + c];
      float nv = ec * ws[OFF_VC + eg*8 + u];
      cls0[u] = (nv + tl) * rden[0];
      cls1[u] = (nv + tr) * rden[1];
      cls2[u] = (nv + bl) * rden[2];
      cls3[u] = (nv + br) * rden[3];
    }
    #pragma unroll
    for (int u = 4; u < 8; ++u) {
      int c = u - 4;
      float tl = PB[c_1j1*4 + c];
      float tr = PB[c_1W*4 + c] - PB[c_1j*4 + c];
      float bl = PB[c_Hj1*4 + c] - PB[c_ij1*4 + c];
      float br = PB[c_HW*4 + c] - PB[c_iW*4 + c] - PB[c_Hj*4 + c] + PB[c_ij*4 + c];
      float nv = ec * ws[OFF_VC + eg*8 + u];
      cls0[u] = (nv + tl) * rden[0];
      cls1[u] = (nv + tr) * rden[1];
      cls2[u] = (nv + bl) * rden[2];
      cls3[u] = (nv + br) * rden[3];
    }
  }
  __syncthreads();

  const unsigned short* gball = (const unsigned short*)(ws + OFF_G);
  const unsigned short* zball = (const unsigned short*)(ws + OFF_Z);

  f32x4 oa0 = {0.f,0.f,0.f,0.f};
  f32x4 oa1 = {0.f,0.f,0.f,0.f};

  int rr = lrow;                      // A-operand row = token 0..15
  int sw3 = (rr & 7) << 3;
  const unsigned short* arh = XNhi + rr*64;
  const unsigned short* arl = XNlo + rr*64;
  const unsigned short* crh = CBhi + rr*128;
  const unsigned short* crl = CBlo + rr*128;

  for (int it = 0; it < 4; ++it) {
    int h0 = it*2;
    // ---- stage1: T[16x128] = XN @ [G_h0 | G_h1] (+v2) ----
    {
      union { bf16x8 v; uint2 d[2]; } ah0, ah1, al0, al1;
      int oa = (quad*8) ^ sw3;
      int ob = (32 + quad*8) ^ sw3;
      ah0.d[0] = *(const uint2*)(arh + oa); ah0.d[1] = *(const uint2*)(arh + oa + 4);
      ah1.d[0] = *(const uint2*)(arh + ob); ah1.d[1] = *(const uint2*)(arh + ob + 4);
      al0.d[0] = *(const uint2*)(arl + oa); al0.d[1] = *(const uint2*)(arl + oa + 4);
      al1.d[0] = *(const uint2*)(arl + ob); al1.d[1] = *(const uint2*)(arl + ob + 4);
      #pragma unroll
      for (int c = 0; c < 4; ++c) {
        int colb = wcol*4 + c;                  // 0..7
        int e0 = colb*16 + lrow;                // 0..127
        // fragment-swizzled G: record = h*8192 + eb*2048 (+1024 half) (+512 lo)
        const unsigned short* gh = gball + (h0 + (colb >> 2))*8192 + (colb & 3)*2048 + lane*8;
        bf16x8 bh0 = *(const bf16x8*)(gh);
        bf16x8 bl0 = *(const bf16x8*)(gh + 512);
        bf16x8 bh1 = *(const bf16x8*)(gh + 1024);
        bf16x8 bl1 = *(const bf16x8*)(gh + 1536);
        f32x4 acc = {0.f,0.f,0.f,0.f};
        __builtin_amdgcn_s_setprio(1);
        acc = __builtin_amdgcn_mfma_f32_16x16x32_bf16(ah0.v, bh0, acc, 0, 0, 0);
        acc = __builtin_amdgcn_mfma_f32_16x16x32_bf16(ah1.v, bh1, acc, 0, 0, 0);
        acc = __builtin_amdgcn_mfma_f32_16x16x32_bf16(al0.v, bh0, acc, 0, 0, 0);
        acc = __builtin_amdgcn_mfma_f32_16x16x32_bf16(al1.v, bh1, acc, 0, 0, 0);
        acc = __builtin_amdgcn_mfma_f32_16x16x32_bf16(ah0.v, bl0, acc, 0, 0, 0);
        acc = __builtin_amdgcn_mfma_f32_16x16x32_bf16(ah1.v, bl1, acc, 0, 0, 0);
        __builtin_amdgcn_s_setprio(0);
        float v2v = ws[OFF_V2 + h0*64 + e0];
        #pragma unroll
        for (int r = 0; r < 4; ++r) {
          int trow = quad*4 + r;               // 0..15
          Tlds[trow*128 + (e0 ^ ((trow & 7) << 2))] = acc[r] + v2v;
        }
      }
    }
    __syncthreads();
    // ---- stage2: both heads' scores -> softmax -> cbar -> split to LDS ----
    {
      float tv0[8], tv1[8];
      {
        int base = tok*128;
        int sw2 = (tok & 7) << 2;
        float4 a0 = *(const float4*)&Tlds[base + ((eg*8) ^ sw2)];
        float4 b0 = *(const float4*)&Tlds[base + ((eg*8 + 4) ^ sw2)];
        float4 a1 = *(const float4*)&Tlds[base + ((64 + eg*8) ^ sw2)];
        float4 b1 = *(const float4*)&Tlds[base + ((64 + eg*8 + 4) ^ sw2)];
        tv0[0]=a0.x; tv0[1]=a0.y; tv0[2]=a0.z; tv0[3]=a0.w;
        tv0[4]=b0.x; tv0[5]=b0.y; tv0[6]=b0.z; tv0[7]=b0.w;
        tv1[0]=a1.x; tv1[1]=a1.y; tv1[2]=a1.z; tv1[3]=a1.w;
        tv1[4]=b1.x; tv1[5]=b1.y; tv1[6]=b1.z; tv1[7]=b1.w;
      }
      float p0=0.f,p1=0.f,p2=0.f,p3=0.f,q0=0.f,q1=0.f,q2=0.f,q3=0.f;
      #pragma unroll
      for (int k = 0; k < 8; ++k) {
        p0 += tv0[k]*cls0[k]; p1 += tv0[k]*cls1[k];
        p2 += tv0[k]*cls2[k]; p3 += tv0[k]*cls3[k];
        q0 += tv1[k]*cls0[k]; q1 += tv1[k]*cls1[k];
        q2 += tv1[k]*cls2[k]; q3 += tv1[k]*cls3[k];
      }
      #pragma unroll
      for (int mk = 1; mk < 8; mk <<= 1) {
        p0 += __shfl_xor(p0, mk, 8); p1 += __shfl_xor(p1, mk, 8);
        p2 += __shfl_xor(p2, mk, 8); p3 += __shfl_xor(p3, mk, 8);
        q0 += __shfl_xor(q0, mk, 8); q1 += __shfl_xor(q1, mk, 8);
        q2 += __shfl_xor(q2, mk, 8); q3 += __shfl_xor(q3, mk, 8);
      }
      union { unsigned u[4]; uint2 d[2]; } ch, cl;
      int cbBase = tok*128;
      int swc = (tok & 7) << 3;
      {
        float s0 = p0*SCALE_RA, s1 = p1*SCALE_RA, s2 = p2*SCALE_RA, s3 = p3*SCALE_RA;
        float mm = fmaxf(fmaxf(s0, s1), fmaxf(s2, s3));
        float e0 = __expf(s0-mm), e1 = __expf(s1-mm), e2 = __expf(s2-mm), e3 = __expf(s3-mm);
        float inv = 1.0f/(e0+e1+e2+e3);
        float av0 = e0*inv, av1 = e1*inv, av2 = e2*inv, av3 = e3*inv;
        #pragma unroll
        for (int k = 0; k < 8; k += 2) {
          float cv0 = av0*cls0[k] + av1*cls1[k] + av2*cls2[k] + av3*cls3[k];
          float cv1 = av0*cls0[k+1] + av1*cls1[k+1] + av2*cls2[k+1] + av3*cls3[k+1];
          split2x2(cv0, cv1, ch.u[k>>1], cl.u[k>>1]);
        }
        int o = cbBase + ((eg*8) ^ swc);
        *(uint2*)&CBhi[o]     = ch.d[0]; *(uint2*)&CBhi[o + 4] = ch.d[1];
        *(uint2*)&CBlo[o]     = cl.d[0]; *(uint2*)&CBlo[o + 4] = cl.d[1];
      }
      {
        float s0 = q0*SCALE_RA, s1 = q1*SCALE_RA, s2 = q2*SCALE_RA, s3 = q3*SCALE_RA;
        float mm = fmaxf(fmaxf(s0, s1), fmaxf(s2, s3));
        float e0 = __expf(s0-mm), e1 = __expf(s1-mm), e2 = __expf(s2-mm), e3 = __expf(s3-mm);
        float inv = 1.0f/(e0+e1+e2+e3);
        float av0 = e0*inv, av1 = e1*inv, av2 = e2*inv, av3 = e3*inv;
        #pragma unroll
        for (int k = 0; k < 8; k += 2) {
          float cv0 = av0*cls0[k] + av1*cls1[k] + av2*cls2[k] + av3*cls3[k];
          float cv1 = av0*cls0[k+1] + av1*cls1[k+1] + av2*cls2[k+1] + av3*cls3[k+1];
          split2x2(cv0, cv1, ch.u[k>>1], cl.u[k>>1]);
        }
        int o = cbBase + ((64 + eg*8) ^ swc);
        *(uint2*)&CBhi[o]     = ch.d[0]; *(uint2*)&CBhi[o + 4] = ch.d[1];
        *(uint2*)&CBlo[o]     = cl.d[0]; *(uint2*)&CBlo[o + 4] = cl.d[1];
      }
    }
    __syncthreads();
    // ---- stage3: OUT(16x64) += CB(16x128) @ [Zt_h0 ; Zt_h1] ----
    {
      #pragma unroll
      for (int c = 0; c < 2; ++c) {
        int colb = wcol*2 + c;                  // 0..3
        int e0 = colb*16 + lrow;                // 0..63
        f32x4 acc = (c == 0) ? oa0 : oa1;
        #pragma unroll
        for (int kb = 0; kb < 4; ++kb) {
          union { bf16x8 v; uint2 d[2]; } ah, al;
          int o = (kb*32 + quad*8) ^ sw3;
          ah.d[0] = *(const uint2*)(crh + o); ah.d[1] = *(const uint2*)(crh + o + 4);
          al.d[0] = *(const uint2*)(crl + o); al.d[1] = *(const uint2*)(crl + o + 4);
          // fragment-swizzled Z: record = h*8192 + colb*2048 + kb1*1024 (+512 lo)
          const unsigned short* zc = zball + (h0 + (kb >> 1))*8192 + colb*2048 + (kb & 1)*1024 + lane*8;
          bf16x8 bh = *(const bf16x8*)(zc);
          bf16x8 bl = *(const bf16x8*)(zc + 512);
          __builtin_amdgcn_s_setprio(1);
          acc = __builtin_amdgcn_mfma_f32_16x16x32_bf16(ah.v, bh, acc, 0, 0, 0);
          acc = __builtin_amdgcn_mfma_f32_16x16x32_bf16(al.v, bh, acc, 0, 0, 0);
          acc = __builtin_amdgcn_mfma_f32_16x16x32_bf16(ah.v, bl, acc, 0, 0, 0);
          __builtin_amdgcn_s_setprio(0);
        }
        if (c == 0) oa0 = acc; else oa1 = acc;
      }
    }
  }
  // epilogue
  #pragma unroll
  for (int c = 0; c < 2; ++c) {
    int e0 = (wcol*2 + c)*16 + lrow;
    float cov = ws[OFF_C1 + e0];
    f32x4 oa = (c == 0) ? oa0 : oa1;
    #pragma unroll
    for (int r = 0; r < 4; ++r)
      outp[(T0 + quad*4 + r)*64 + e0] = oa[r] + cov;
  }
}

extern "C" void kernel_launch(void* const* d_in, const int* in_sizes, int n_in,
                              void* d_out, int out_size, void* d_ws, size_t ws_size,
                              hipStream_t stream) {
  const float* x      = (const float*)d_in[0];
  const float* ln_g   = (const float*)d_in[1];
  const float* ln_b   = (const float*)d_in[2];
  const float* Wqkv   = (const float*)d_in[3];
  const float* bqkv   = (const float*)d_in[4];
  const float* cls_tok= (const float*)d_in[5];
  const float* Wwqkv  = (const float*)d_in[6];
  const float* bwqkv  = (const float*)d_in[7];
  const float* Wwproj = (const float*)d_in[8];
  const float* bwproj = (const float*)d_in[9];
  const float* Wraq   = (const float*)d_in[10];
  const float* Wrak   = (const float*)d_in[11];
  const float* Wrav   = (const float*)d_in[12];
  const float* Wrao   = (const float*)d_in[13];
  const float* brao   = (const float*)d_in[14];
  const float* Wout   = (const float*)d_in[15];
  const float* bout   = (const float*)d_in[16];
  float* ws = (float*)d_ws;
  float* outp = (float*)d_out;

  hipLaunchKernelGGL(k_pre, dim3(2321), dim3(256), 0, stream,
                     x, ln_g, ln_b, Wqkv, bqkv, cls_tok, Wwqkv, bwqkv,
                     Wwproj, bwproj, Wraq, Wrak, Wrav, Wrao, brao, Wout, bout, ws);
  hipLaunchKernelGGL(k_prefix, dim3(512), dim3(512), 0, stream, ws);
  hipLaunchKernelGGL(k_main, dim3(9216), dim3(128), 0, stream, ws, outp);
}

// Round 15
// 324.021 us; speedup vs baseline: 1.0699x; 1.0098x over previous
//
#include <hip/hip_runtime.h>
#include <math.h>

// FourRegionAttention on MI355X (gfx950). B=64, n=2304 (48x48), D=64, h=8, hd=8.
// 3-kernel pipeline: k_pre (fused setup1+setupW+lnkv; setup blocks FIRST;
// KT/VT staged through XOR-swizzled LDS; XN intermediate ELIMINATED - k_main
// recomputes LN inline from x, saving a 37.7MB HBM write) -> k_prefix
// (512 blocks, one per bh) -> k_main (16-tok blocks, fragment-swizzled G/Z;
// XCD-chunked blockIdx swizzle [FETCH 94->41MB, r12] + s_setprio).
// r13's double-buffer REGRESSED (TLP loss) -> single-buffer form kept.
// k_main A-fragments re-read from LDS per iteration (r7 hoist regressed).
// NOTE: no min-waves arg on __launch_bounds__ (spill hazard, r1-r2).

#define SCALE_W  0.3535533905932738f   // 8^-0.5
#define SCALE_RA 0.3535533905932738f
#define LN_EPS 1e-5f

typedef __attribute__((ext_vector_type(8))) short bf16x8;
typedef __attribute__((ext_vector_type(4))) float f32x4;

// ---- workspace layout (float offsets) ----
#define OFF_XN   0ull
#define SZ_XN    (64ull*2304*64)            // (region now unused; layout kept)
#define OFF_KT   (OFF_XN + SZ_XN)           // k_t [b][h][n][8]
#define SZ_KT    (64ull*8*2304*8)           // 9437184
#define OFF_VT   (OFF_KT + SZ_KT)           // v_t [b][h][n][8]
#define OFF_PA   (OFF_VT + SZ_KT)           // PA [bh][2401][5]: e, e*v[0..3] prefix
#define SZ_PA    (512ull*2401*5)
#define OFF_PB   (OFF_PA + SZ_PA)           // PB [bh][2401][4]: e*v[4..7] prefix
#define SZ_PB    (512ull*2401*4)
#define OFF_ECLS (OFF_PB + SZ_PB)           // 512
#define OFF_QC   (OFF_ECLS + 512)           // 64 (scaled q_c)
#define OFF_KC   (OFF_QC + 64)              // 64
#define OFF_VC   (OFF_KC + 64)              // 64
#define OFF_CLOG (OFF_VC + 64)              // 8
#define OFF_BK   (OFF_CLOG + 8)             // 64  (dead - kept for layout)
#define OFF_BV   (OFF_BK + 64)              // 64
#define OFF_AH   (OFF_BV + 64)              // 512 a_h = Wraq@bqkv_h
#define OFF_W1   (OFF_AH + 512)             // 64  (dead - kept for layout)
#define OFF_WZ   (OFF_W1 + 64)              // 64  Wrao@bv
#define OFF_B2   (OFF_WZ + 64)              // 512 Wrak^T@a_h
#define OFF_V2   (OFF_B2 + 512)             // 512 v2_h
#define OFF_UH   (OFF_V2 + 512)             // 512 (dead - kept for layout)
#define OFF_CH   (OFF_UH + 512)             // 8   (dead - kept for layout)
#define OFF_C1   (OFF_CH + 8)               // 64  const output bias
// GB/ZB: per head 8192 ushorts = 16 records x 512 ushorts (1KB each).
// record idx within head: tile(e>>4)*2048 + half(d>>5)*1024 + plane*512,
// entry: lane = ((d>>3)&3)*16 + (e&15), j = d&7  (fragment lane-major).
#define OFF_G    (OFF_C1 + 64)              // 32768 floats
#define OFF_Z    (OFF_G + 32768)            // 32768 floats

__device__ inline void split2(float x, unsigned short &h, unsigned short &l) {
  unsigned u = __float_as_uint(x);
  unsigned hr = (u + 0x7fffu + ((u >> 16) & 1u)) >> 16;
  h = (unsigned short)hr;
  float hf = __uint_as_float(hr << 16);
  float lo = x - hf;
  unsigned u2 = __float_as_uint(lo);
  l = (unsigned short)((u2 + 0x7fffu + ((u2 >> 16) & 1u)) >> 16);
}

// split a pair of floats into packed bf16 hi words + packed bf16 lo-residual
// words using the HW packed converter (RNE, same rounding as split2).
__device__ inline void split2x2(float x0, float x1, unsigned &h, unsigned &l) {
  asm("v_cvt_pk_bf16_f32 %0, %1, %2" : "=v"(h) : "v"(x0), "v"(x1));
  float r0 = x0 - __uint_as_float(h << 16);
  float r1 = x1 - __uint_as_float(h & 0xffff0000u);
  asm("v_cvt_pk_bf16_f32 %0, %1, %2" : "=v"(l) : "v"(r0), "v"(r1));
}

__device__ inline float dot64(const float* __restrict__ a, const float* __restrict__ b) {
  float s0 = 0.f, s1 = 0.f, s2 = 0.f, s3 = 0.f;
  #pragma unroll
  for (int d = 0; d < 64; d += 4) {
    float4 av = *(const float4*)(a + d);
    float4 bv = *(const float4*)(b + d);
    s0 += av.x * bv.x; s1 += av.y * bv.y;
    s2 += av.z * bv.z; s3 += av.w * bv.w;
  }
  return (s0 + s1) + (s2 + s3);
}

// ---------------- fused pre-kernel: setup1 (blk 0) | setupW (1..16) | lnkv (17..2320) ----------------
__global__ __launch_bounds__(256) void k_pre(const float* __restrict__ x,
      const float* __restrict__ ln_g, const float* __restrict__ ln_b,
      const float* __restrict__ Wqkv, const float* __restrict__ bqkv,
      const float* __restrict__ cls_tok, const float* __restrict__ Wwqkv,
      const float* __restrict__ bwqkv, const float* __restrict__ Wwproj,
      const float* __restrict__ bwproj, const float* __restrict__ Wraq,
      const float* __restrict__ Wrak, const float* __restrict__ Wrav,
      const float* __restrict__ Wrao, const float* __restrict__ brao,
      const float* __restrict__ Wout, const float* __restrict__ bout,
      float* __restrict__ ws) {
  __shared__ float smu[12928];   // union: lnkv 12928 | setupW 8320 | setup1 64 | kv-stage 8192
  int tid = threadIdx.x;
  int blk = blockIdx.x;

  if (blk >= 17) {
    // ======== LayerNorm + k/v GEMM (XN no longer stored to global) ========
    float* xnT = smu;                 // [d][68]
    float* xt  = smu + 4352;          // [tok][65]
    float* wkv = smu + 4352;          // [d][132]
    float* muL = smu + 4352 + 8448;
    float* rsL = muL + 64;

    long T0 = (long)(blk - 17) * 64;
    int tok = tid >> 2, seg = tid & 3;

    const float4* x4 = (const float4*)(x + (T0 + tok)*64 + seg*16);
    float4 va = x4[0], vb = x4[1], vc4 = x4[2], vd = x4[3];
    {
      float* xp = xt + tok*65 + seg*16;
      xp[0]=va.x; xp[1]=va.y; xp[2]=va.z; xp[3]=va.w;
      xp[4]=vb.x; xp[5]=vb.y; xp[6]=vb.z; xp[7]=vb.w;
      xp[8]=vc4.x; xp[9]=vc4.y; xp[10]=vc4.z; xp[11]=vc4.w;
      xp[12]=vd.x; xp[13]=vd.y; xp[14]=vd.z; xp[15]=vd.w;
    }
    __syncthreads();
    if (tid < 64) {
      float s = 0.f;
      for (int i2 = 0; i2 < 64; ++i2) s += xt[tid*65 + i2];
      float mu = s * (1.0f/64.0f);
      float v = 0.f;
      for (int i2 = 0; i2 < 64; ++i2) { float d = xt[tid*65 + i2] - mu; v += d*d; }
      v *= (1.0f/64.0f);
      muL[tid] = mu; rsL[tid] = 1.0f / sqrtf(v + LN_EPS);
    }
    __syncthreads();
    {
      float mu = muL[tok], rs = rsL[tok];
      #pragma unroll
      for (int k = 0; k < 16; ++k) {
        int i2 = seg*16 + k;
        float v = (xt[tok*65 + i2] - mu) * rs * ln_g[i2] + ln_b[i2];
        xnT[i2*68 + tok] = v;
      }
    }
    __syncthreads();
    {
      int o = tid >> 1, dh = (tid & 1) * 32;
      #pragma unroll
      for (int k = 0; k < 32; k += 4) {
        float4 w4 = *(const float4*)(Wwqkv + (64 + o)*64 + dh + k);
        wkv[(dh+k+0)*132 + o] = w4.x;
        wkv[(dh+k+1)*132 + o] = w4.y;
        wkv[(dh+k+2)*132 + o] = w4.z;
        wkv[(dh+k+3)*132 + o] = w4.w;
      }
    }
    __syncthreads();
    int tokq = tid & 15, og = tid >> 4;
    float acc[4][8];
    #pragma unroll
    for (int ti = 0; ti < 4; ++ti)
      #pragma unroll
      for (int k = 0; k < 8; ++k) acc[ti][k] = 0.f;
    for (int d2 = 0; d2 < 64; ++d2) {
      float4 a4 = *(float4*)&xnT[d2*68 + tokq*4];
      float4 b0 = *(float4*)&wkv[d2*132 + og*8];
      float4 b1 = *(float4*)&wkv[d2*132 + og*8 + 4];
      float aa[4] = {a4.x, a4.y, a4.z, a4.w};
      float bbv[8] = {b0.x,b0.y,b0.z,b0.w,b1.x,b1.y,b1.z,b1.w};
      #pragma unroll
      for (int ti = 0; ti < 4; ++ti)
        #pragma unroll
        for (int k = 0; k < 8; ++k) acc[ti][k] += aa[ti]*bbv[k];
    }
    float bsv[8];
    #pragma unroll
    for (int k = 0; k < 8; ++k) bsv[k] = bwqkv[64 + og*8 + k];
    // ---- stage into XOR-swizzled LDS, then fully-coalesced global stores ----
    __syncthreads();                       // all xnT/wkv reads done
    float4* kvb = (float4*)smu;            // 2048 float4 = 8192 floats
    #pragma unroll
    for (int ti = 0; ti < 4; ++ti) {
      int ntok = tokq*4 + ti;
      int L0 = og*128 + ntok*2;
      int p0 = L0 ^ ((L0 >> 3) & 7);
      int p1 = (L0 + 1) ^ (((L0 + 1) >> 3) & 7);
      kvb[p0] = make_float4(acc[ti][0]+bsv[0], acc[ti][1]+bsv[1], acc[ti][2]+bsv[2], acc[ti][3]+bsv[3]);
      kvb[p1] = make_float4(acc[ti][4]+bsv[4], acc[ti][5]+bsv[5], acc[ti][6]+bsv[6], acc[ti][7]+bsv[7]);
    }
    __syncthreads();
    int bb = (int)(T0 / 2304);
    int nlbase = (int)(T0 % 2304);
    #pragma unroll
    for (int r = 0; r < 8; ++r) {
      int L = tid + r*256;
      int ogr = L >> 7;
      int hhr = ogr & 7;
      int ntok = (L >> 1) & 63;
      int cc = L & 1;
      int phys = L ^ ((L >> 3) & 7);
      float4 val = kvb[phys];
      unsigned long long dstoff = (ogr < 8) ? OFF_KT : OFF_VT;
      float* dst = ws + dstoff + ((long)(bb*8 + hhr)*2304 + (nlbase + ntok))*8 + cc*4;
      *(float4*)dst = val;
    }
  } else if (blk >= 1) {
    // ======== per-head G/Z chains -> fragment-swizzled bf16 ========
    float* A  = smu;
    float* Bl = smu + 4160;
    int wblk = blk - 1;
    if (wblk < 8) {
      int hh = wblk;
      for (int o = tid; o < 4096; o += 256) {
        int d = o & 63, e = o >> 6; float s = 0.f;
        for (int f = 0; f < 64; ++f) s += Wraq[f*64+d] * Wrak[f*64+e];
        A[d*65 + e] = s;
      }
      __syncthreads();
      for (int o = tid; o < 4096; o += 256) {
        int j = o & 63, i = o >> 6; float s = 0.f;
        for (int f = 0; f < 64; ++f) s += A[i*65 + f] * Wwproj[f*64 + j];
        Bl[i*65 + j] = s;
      }
      __syncthreads();
      unsigned short* gb = (unsigned short*)(ws + OFF_G) + hh*8192;
      for (int o = tid; o < 4096; o += 256) {
        int d = o & 63, e = o >> 6; float s = 0.f;
        for (int f = 0; f < 64; ++f) s += Wqkv[(hh*64+f)*64 + d] * Bl[f*65 + e];
        unsigned short h16, l16;
        split2(s, h16, l16);
        int base = (e >> 4)*2048 + (d >> 5)*1024 + (((d >> 3) & 3)*16 + (e & 15))*8 + (d & 7);
        gb[base]       = h16;   // plane hi
        gb[base + 512] = l16;   // plane lo
      }
    } else {
      int hh = wblk - 8;
      for (int o = tid; o < 4096; o += 256) {
        int d = o & 63, e = o >> 6; float s = 0.f;
        for (int f = 0; f < 64; ++f) s += Wrav[e*64+f] * Wwproj[f*64+d];
        A[e*65 + d] = s;
      }
      __syncthreads();
      for (int o = tid; o < 4096; o += 256) {
        int d = o & 63, i = o >> 6; float s = 0.f;
        for (int f = 0; f < 64; ++f) s += Wrao[i*64+f] * A[f*65 + d];
        Bl[i*65 + d] = s;
      }
      __syncthreads();
      unsigned short* zb = (unsigned short*)(ws + OFF_Z) + hh*8192;
      for (int o = tid; o < 4096; o += 256) {
        int d = o & 63, e = o >> 6; float s = 0.f;  // d = channel, e = out-dim
        for (int f = 0; f < 64; ++f) s += Wout[e*512 + hh*64 + f] * Bl[f*65 + d];
        unsigned short h16, l16;
        split2(s, h16, l16);
        int base = (e >> 4)*2048 + (d >> 5)*1024 + (((d >> 3) & 3)*16 + (e & 15))*8 + (d & 7);
        zb[base]       = h16;
        zb[base + 512] = l16;
      }
    }
  } else {
    // ======== small folded vectors (single block) ========
    float* bwz = smu;
    for (int idx = tid; idx < 768; idx += 256) {
      if (idx < 192) {
        float s = bwqkv[idx] + dot64(Wwqkv + idx*64, cls_tok);
        if (idx < 64) ws[OFF_QC + idx] = s * SCALE_W;
        else if (idx < 128) ws[OFF_KC + idx - 64] = s;
        else ws[OFF_VC + idx - 128] = s;
      } else if (idx < 256) {
        int e = idx - 192;
        ws[OFF_BV + e] = dot64(Wrav + e*64, bwproj);
      } else {
        int t2 = idx - 256; int hh = t2 >> 6, e = t2 & 63;
        ws[OFF_AH + t2] = dot64(Wraq + e*64, bqkv + hh*64);
      }
    }
    __syncthreads();
    for (int idx = tid; idx < 584; idx += 256) {
      if (idx < 8) {
        float s = 0.f;
        for (int u = 0; u < 8; ++u) s += ws[OFF_QC + idx*8+u] * ws[OFF_KC + idx*8+u];
        ws[OFF_CLOG + idx] = s;
      } else if (idx < 72) {
        int e = idx - 8;
        ws[OFF_WZ + e] = dot64(Wrao + e*64, ws + OFF_BV);
      } else {
        int t2 = idx - 72; int hh = t2 >> 6, e = t2 & 63; float s = 0.f;
        for (int d = 0; d < 64; ++d) s += Wrak[d*64+e] * ws[OFF_AH + hh*64+d];
        ws[OFF_B2 + t2] = s;
      }
    }
    __syncthreads();
    if (tid < 64) bwz[tid] = brao[tid] + ws[OFF_WZ + tid];
    __syncthreads();
    for (int idx = tid; idx < 576; idx += 256) {
      if (idx < 512) {
        int hh = idx >> 6, e = idx & 63; float s = 0.f;
        for (int d = 0; d < 64; ++d) s += Wwproj[d*64+e] * ws[OFF_B2 + hh*64+d];
        ws[OFF_V2 + idx] = s;
      } else {
        int e = idx - 512;
        float s0 = 0.f, s1 = 0.f, s2 = 0.f, s3 = 0.f;
        for (int f = 0; f < 512; f += 4) {
          float4 w4 = *(const float4*)(Wout + e*512 + f);
          float4 b4 = *(const float4*)&bwz[f & 63];
          s0 += w4.x*b4.x; s1 += w4.y*b4.y; s2 += w4.z*b4.z; s3 += w4.w*b4.w;
        }
        ws[OFF_C1 + e] = bout[e] + (s0 + s1) + (s2 + s3);
      }
    }
  }
}

// ---------------- logits + softmax-normalizer + 2D prefix sums ----------------
__global__ __launch_bounds__(512) void k_prefix(float* __restrict__ ws) {
  __shared__ float Pp[49*49*5];
  __shared__ float red[8];
  int tid = threadIdx.x;
  int bh = blockIdx.x;
  int hh = bh & 7;
  const float* kt = ws + OFF_KT + (long)bh*2304*8;
  const float* vt = ws + OFF_VT + (long)bh*2304*8;
  float qc[8];
  #pragma unroll
  for (int u = 0; u < 8; ++u) qc[u] = ws[OFF_QC + hh*8 + u];
  float ev[5];
  float mloc = -1e30f;
  #pragma unroll
  for (int it = 0; it < 5; ++it) {
    int nn = tid + it*512;
    if (nn < 2304) {
      const float4* kk = (const float4*)(kt + nn*8);
      float4 k0 = kk[0], k1 = kk[1];
      float lv = qc[0]*k0.x + qc[1]*k0.y + qc[2]*k0.z + qc[3]*k0.w
               + qc[4]*k1.x + qc[5]*k1.y + qc[6]*k1.z + qc[7]*k1.w;
      ev[it] = lv;
      mloc = fmaxf(mloc, lv);
    }
  }
  #pragma unroll
  for (int mk = 1; mk < 64; mk <<= 1) mloc = fmaxf(mloc, __shfl_xor(mloc, mk, 64));
  if ((tid & 63) == 0) red[tid >> 6] = mloc;
  __syncthreads();
  float m = fmaxf(fmaxf(fmaxf(red[0], red[1]), fmaxf(red[2], red[3])),
                  fmaxf(fmaxf(red[4], red[5]), fmaxf(red[6], red[7])));
  m = fmaxf(m, ws[OFF_CLOG + hh]);
  if (tid == 0) ws[OFF_ECLS + bh] = __expf(ws[OFF_CLOG + hh] - m);
  #pragma unroll
  for (int it = 0; it < 5; ++it) {
    int nn = tid + it*512;
    if (nn < 2304) ev[it] = __expf(ev[it] - m);
  }
  // ---- pass A: columns [e, e*v0..3] ----
  #pragma unroll
  for (int it = 0; it < 5; ++it) {
    int nn = tid + it*512;
    if (nn < 2304) {
      int i2 = nn / 48, j2 = nn % 48;
      float4 v4 = *(const float4*)(vt + nn*8);
      float* cell = &Pp[((i2+1)*49 + (j2+1))*5];
      float e0 = ev[it];
      cell[0] = e0; cell[1] = e0*v4.x; cell[2] = e0*v4.y; cell[3] = e0*v4.z; cell[4] = e0*v4.w;
    }
  }
  __syncthreads();
  if (tid < 240) {
    int j2 = tid / 5 + 1, c = tid % 5;
    float s = 0.f;
    for (int i0 = 1; i0 <= 48; i0 += 8) {
      float v[8];
      #pragma unroll
      for (int k = 0; k < 8; ++k) v[k] = Pp[((i0+k)*49 + j2)*5 + c];
      #pragma unroll
      for (int k = 0; k < 8; ++k) { s += v[k]; v[k] = s; }
      #pragma unroll
      for (int k = 0; k < 8; ++k) Pp[((i0+k)*49 + j2)*5 + c] = v[k];
    }
  }
  __syncthreads();
  if (tid < 240) {
    int i2 = tid / 5 + 1, c = tid % 5;
    float s = 0.f;
    for (int j0 = 1; j0 <= 48; j0 += 8) {
      float v[8];
      #pragma unroll
      for (int k = 0; k < 8; ++k) v[k] = Pp[(i2*49 + j0+k)*5 + c];
      #pragma unroll
      for (int k = 0; k < 8; ++k) { s += v[k]; v[k] = s; }
      #pragma unroll
      for (int k = 0; k < 8; ++k) Pp[(i2*49 + j0+k)*5 + c] = v[k];
    }
  }
  __syncthreads();
  {
    float* pa = ws + OFF_PA + (long)bh*12005;
    for (int idx = tid; idx < 12005; idx += 512) {
      int cell = idx / 5;
      int ii = cell / 49, jj = cell % 49;
      pa[idx] = (ii && jj) ? Pp[idx] : 0.f;
    }
  }
  __syncthreads();
  // ---- pass B: columns [e*v4..7] (stride-5 layout, 4 used) ----
  #pragma unroll
  for (int it = 0; it < 5; ++it) {
    int nn = tid + it*512;
    if (nn < 2304) {
      int i2 = nn / 48, j2 = nn % 48;
      float4 v4 = *(const float4*)(vt + nn*8 + 4);
      float* cell = &Pp[((i2+1)*49 + (j2+1))*5];
      float e0 = ev[it];
      cell[0] = e0*v4.x; cell[1] = e0*v4.y; cell[2] = e0*v4.z; cell[3] = e0*v4.w;
    }
  }
  __syncthreads();
  if (tid < 192) {
    int j2 = tid >> 2, c = tid & 3; j2 += 1;
    float s = 0.f;
    for (int i0 = 1; i0 <= 48; i0 += 8) {
      float v[8];
      #pragma unroll
      for (int k = 0; k < 8; ++k) v[k] = Pp[((i0+k)*49 + j2)*5 + c];
      #pragma unroll
      for (int k = 0; k < 8; ++k) { s += v[k]; v[k] = s; }
      #pragma unroll
      for (int k = 0; k < 8; ++k) Pp[((i0+k)*49 + j2)*5 + c] = v[k];
    }
  }
  __syncthreads();
  if (tid < 192) {
    int i2 = tid >> 2, c = tid & 3; i2 += 1;
    float s = 0.f;
    for (int j0 = 1; j0 <= 48; j0 += 8) {
      float v[8];
      #pragma unroll
      for (int k = 0; k < 8; ++k) v[k] = Pp[(i2*49 + j0+k)*5 + c];
      #pragma unroll
      for (int k = 0; k < 8; ++k) { s += v[k]; v[k] = s; }
      #pragma unroll
      for (int k = 0; k < 8; ++k) Pp[(i2*49 + j0+k)*5 + c] = v[k];
    }
  }
  __syncthreads();
  {
    float* pb = ws + OFF_PB + (long)bh*9604;
    for (int idx = tid; idx < 9604; idx += 512) {
      int cell = idx >> 2, c = idx & 3;
      int ii = cell / 49, jj = cell % 49;
      pb[idx] = (ii && jj) ? Pp[cell*5 + c] : 0.f;
    }
  }
}

// ---------------- main fused kernel (MFMA, 2 heads/iter) ----------------
// grid 9216 x 128 threads, 16 tokens/block, 2 waves. LDS 20480 B.
// LN recomputed inline from x (8-lane shfl reduce; kills the XN roundtrip).
// XCD-chunked blockIdx swizzle (9216%8==0, bijective).
// G/Z fragment loads: base + lane*16B -> one coalesced dwordx4 per fragment.
__global__ __launch_bounds__(128) void k_main(const float* __restrict__ x,
                                              const float* __restrict__ ln_g,
                                              const float* __restrict__ ln_b,
                                              const float* __restrict__ ws,
                                              float* __restrict__ outp) {
  __shared__ __align__(16) unsigned short XNhi[16*64];
  __shared__ __align__(16) unsigned short XNlo[16*64];
  __shared__ __align__(16) unsigned short CBhi[16*128];
  __shared__ __align__(16) unsigned short CBlo[16*128];
  __shared__ __align__(16) float Tlds[16*128];

  int tid = threadIdx.x;
  int tok = tid >> 3, eg = tid & 7;       // 16 tok x 8 eg
  int lane = tid & 63, wv = tid >> 6;     // 2 waves
  int quad = lane >> 4, lrow = lane & 15;
  int wcol = wv;
  int bid = blockIdx.x;
  int bswz = (bid & 7) * 1152 + (bid >> 3);   // XCD-chunked, bijective on 9216
  long T0 = (long)bswz * 16;
  int b = (int)(T0 / 2304);
  int n = (int)(T0 % 2304) + tok;
  int i2 = n / 48, j2 = n % 48;

  // x slice -> inline LN (8-lane shfl) -> split -> LDS (swizzled)
  {
    const float4* p4 = (const float4*)(x + (T0 + tok)*64 + eg*8);
    float4 xa = p4[0], xb = p4[1];
    float xv[8] = {xa.x, xa.y, xa.z, xa.w, xb.x, xb.y, xb.z, xb.w};
    float s = 0.f;
    #pragma unroll
    for (int k = 0; k < 8; ++k) s += xv[k];
    s += __shfl_xor(s, 1, 8);
    s += __shfl_xor(s, 2, 8);
    s += __shfl_xor(s, 4, 8);
    float mu = s * (1.0f/64.0f);
    float vv = 0.f;
    #pragma unroll
    for (int k = 0; k < 8; ++k) { float d = xv[k] - mu; vv += d*d; }
    vv += __shfl_xor(vv, 1, 8);
    vv += __shfl_xor(vv, 2, 8);
    vv += __shfl_xor(vv, 4, 8);
    float rs = 1.0f / sqrtf(vv * (1.0f/64.0f) + LN_EPS);
    const float4* g4 = (const float4*)(ln_g + eg*8);
    const float4* b4 = (const float4*)(ln_b + eg*8);
    float4 ga = g4[0], gb = g4[1];
    float4 ba = b4[0], bb = b4[1];
    float gr[8] = {ga.x,ga.y,ga.z,ga.w, gb.x,gb.y,gb.z,gb.w};
    float br[8] = {ba.x,ba.y,ba.z,ba.w, bb.x,bb.y,bb.z,bb.w};
    union { unsigned u[4]; uint2 d[2]; } ph, pl;
    #pragma unroll
    for (int k = 0; k < 8; k += 2) {
      float v0 = (xv[k]   - mu) * rs * gr[k]   + br[k];
      float v1 = (xv[k+1] - mu) * rs * gr[k+1] + br[k+1];
      split2x2(v0, v1, ph.u[k>>1], pl.u[k>>1]);
    }
    int off = tok*64 + ((eg*8) ^ ((tok & 7) << 3));
    *(uint2*)&XNhi[off]     = ph.d[0];
    *(uint2*)&XNhi[off + 4] = ph.d[1];
    *(uint2*)&XNlo[off]     = pl.d[0];
    *(uint2*)&XNlo[off + 4] = pl.d[1];
  }

  // phase0: cls slice in registers (source-head eg, channels eg*8..+8, 4 regions)
  float cls0[8], cls1[8], cls2[8], cls3[8];
  {
    float ec = ws[OFF_ECLS + b*8 + eg];
    const float* PA = ws + OFF_PA + (long)(b*8 + eg)*12005;
    const float* PB = ws + OFF_PB + (long)(b*8 + eg)*9604;
    int c_ij  = i2*49 + j2;
    int c_ij1 = c_ij + 1;
    int c_iW  = i2*49 + 48;
    int c_1j  = c_ij + 49;
    int c_1j1 = c_1j + 1;
    int c_1W  = c_iW + 49;
    int c_Hj  = 48*49 + j2;
    int c_Hj1 = c_Hj + 1;
    int c_HW  = 48*49 + 48;
    float rden[4];
    {
      float tl = PA[c_1j1*5];
      float tr = PA[c_1W*5] - PA[c_1j*5];
      float bl = PA[c_Hj1*5] - PA[c_ij1*5];
      float br = PA[c_HW*5] - PA[c_iW*5] - PA[c_Hj*5] + PA[c_ij*5];
      rden[0] = 1.0f/(ec + tl); rden[1] = 1.0f/(ec + tr);
      rden[2] = 1.0f/(ec + bl); rden[3] = 1.0f/(ec + br);
    }
    #pragma unroll
    for (int u = 0; u < 4; ++u) {
      int c = 1 + u;
      float tl = PA[c_1j1*5 + c];
      float tr = PA[c_1W*5 + c] - PA[c_1j*5 + c];
      float bl = PA[c_Hj1*5 + c] - PA[c_ij1*5 + c];
      float br = PA[c_HW*5 + c] - PA[c_iW*5 + c] - PA[c_Hj*5 + c] + PA[c_ij*5 + c];
      float nv = ec * ws[OFF_VC + eg*8 + u];
      cls0[u] = (nv + tl) * rden[0];
      cls1[u] = (nv + tr) * rden[1];
      cls2[u] = (nv + bl) * rden[2];
      cls3[u] = (nv + br) * rden[3];
    }
    #pragma unroll
    for (int u = 4; u < 8; ++u) {
      int c = u - 4;
      float tl = PB[c_1j1*4 + c];
      float tr = PB[c_1W*4 + c] - PB[c_1j*4 + c];
      float bl = PB[c_Hj1*4 + c] - PB[c_ij1*4 + c];
      float br = PB[c_HW*4 + c] - PB[c_iW*4 + c] - PB[c_Hj*4 + c] + PB[c_ij*4 + c];
      float nv = ec * ws[OFF_VC + eg*8 + u];
      cls0[u] = (nv + tl) * rden[0];
      cls1[u] = (nv + tr) * rden[1];
      cls2[u] = (nv + bl) * rden[2];
      cls3[u] = (nv + br) * rden[3];
    }
  }
  __syncthreads();

  const unsigned short* gball = (const unsigned short*)(ws + OFF_G);
  const unsigned short* zball = (const unsigned short*)(ws + OFF_Z);

  f32x4 oa0 = {0.f,0.f,0.f,0.f};
  f32x4 oa1 = {0.f,0.f,0.f,0.f};

  int rr = lrow;                      // A-operand row = token 0..15
  int sw3 = (rr & 7) << 3;
  const unsigned short* arh = XNhi + rr*64;
  const unsigned short* arl = XNlo + rr*64;
  const unsigned short* crh = CBhi + rr*128;
  const unsigned short* crl = CBlo + rr*128;

  for (int it = 0; it < 4; ++it) {
    int h0 = it*2;
    // ---- stage1: T[16x128] = XN @ [G_h0 | G_h1] (+v2) ----
    {
      union { bf16x8 v; uint2 d[2]; } ah0, ah1, al0, al1;
      int oa = (quad*8) ^ sw3;
      int ob = (32 + quad*8) ^ sw3;
      ah0.d[0] = *(const uint2*)(arh + oa); ah0.d[1] = *(const uint2*)(arh + oa + 4);
      ah1.d[0] = *(const uint2*)(arh + ob); ah1.d[1] = *(const uint2*)(arh + ob + 4);
      al0.d[0] = *(const uint2*)(arl + oa); al0.d[1] = *(const uint2*)(arl + oa + 4);
      al1.d[0] = *(const uint2*)(arl + ob); al1.d[1] = *(const uint2*)(arl + ob + 4);
      #pragma unroll
      for (int c = 0; c < 4; ++c) {
        int colb = wcol*4 + c;                  // 0..7
        int e0 = colb*16 + lrow;                // 0..127
        // fragment-swizzled G: record = h*8192 + eb*2048 (+1024 half) (+512 lo)
        const unsigned short* gh = gball + (h0 + (colb >> 2))*8192 + (colb & 3)*2048 + lane*8;
        bf16x8 bh0 = *(const bf16x8*)(gh);
        bf16x8 bl0 = *(const bf16x8*)(gh + 512);
        bf16x8 bh1 = *(const bf16x8*)(gh + 1024);
        bf16x8 bl1 = *(const bf16x8*)(gh + 1536);
        f32x4 acc = {0.f,0.f,0.f,0.f};
        __builtin_amdgcn_s_setprio(1);
        acc = __builtin_amdgcn_mfma_f32_16x16x32_bf16(ah0.v, bh0, acc, 0, 0, 0);
        acc = __builtin_amdgcn_mfma_f32_16x16x32_bf16(ah1.v, bh1, acc, 0, 0, 0);
        acc = __builtin_amdgcn_mfma_f32_16x16x32_bf16(al0.v, bh0, acc, 0, 0, 0);
        acc = __builtin_amdgcn_mfma_f32_16x16x32_bf16(al1.v, bh1, acc, 0, 0, 0);
        acc = __builtin_amdgcn_mfma_f32_16x16x32_bf16(ah0.v, bl0, acc, 0, 0, 0);
        acc = __builtin_amdgcn_mfma_f32_16x16x32_bf16(ah1.v, bl1, acc, 0, 0, 0);
        __builtin_amdgcn_s_setprio(0);
        float v2v = ws[OFF_V2 + h0*64 + e0];
        #pragma unroll
        for (int r = 0; r < 4; ++r) {
          int trow = quad*4 + r;               // 0..15
          Tlds[trow*128 + (e0 ^ ((trow & 7) << 2))] = acc[r] + v2v;
        }
      }
    }
    __syncthreads();
    // ---- stage2: both heads' scores -> softmax -> cbar -> split to LDS ----
    {
      float tv0[8], tv1[8];
      {
        int base = tok*128;
        int sw2 = (tok & 7) << 2;
        float4 a0 = *(const float4*)&Tlds[base + ((eg*8) ^ sw2)];
        float4 b0 = *(const float4*)&Tlds[base + ((eg*8 + 4) ^ sw2)];
        float4 a1 = *(const float4*)&Tlds[base + ((64 + eg*8) ^ sw2)];
        float4 b1 = *(const float4*)&Tlds[base + ((64 + eg*8 + 4) ^ sw2)];
        tv0[0]=a0.x; tv0[1]=a0.y; tv0[2]=a0.z; tv0[3]=a0.w;
        tv0[4]=b0.x; tv0[5]=b0.y; tv0[6]=b0.z; tv0[7]=b0.w;
        tv1[0]=a1.x; tv1[1]=a1.y; tv1[2]=a1.z; tv1[3]=a1.w;
        tv1[4]=b1.x; tv1[5]=b1.y; tv1[6]=b1.z; tv1[7]=b1.w;
      }
      float p0=0.f,p1=0.f,p2=0.f,p3=0.f,q0=0.f,q1=0.f,q2=0.f,q3=0.f;
      #pragma unroll
      for (int k = 0; k < 8; ++k) {
        p0 += tv0[k]*cls0[k]; p1 += tv0[k]*cls1[k];
        p2 += tv0[k]*cls2[k]; p3 += tv0[k]*cls3[k];
        q0 += tv1[k]*cls0[k]; q1 += tv1[k]*cls1[k];
        q2 += tv1[k]*cls2[k]; q3 += tv1[k]*cls3[k];
      }
      #pragma unroll
      for (int mk = 1; mk < 8; mk <<= 1) {
        p0 += __shfl_xor(p0, mk, 8); p1 += __shfl_xor(p1, mk, 8);
        p2 += __shfl_xor(p2, mk, 8); p3 += __shfl_xor(p3, mk, 8);
        q0 += __shfl_xor(q0, mk, 8); q1 += __shfl_xor(q1, mk, 8);
        q2 += __shfl_xor(q2, mk, 8); q3 += __shfl_xor(q3, mk, 8);
      }
      union { unsigned u[4]; uint2 d[2]; } ch, cl;
      int cbBase = tok*128;
      int swc = (tok & 7) << 3;
      {
        float s0 = p0*SCALE_RA, s1 = p1*SCALE_RA, s2 = p2*SCALE_RA, s3 = p3*SCALE_RA;
        float mm = fmaxf(fmaxf(s0, s1), fmaxf(s2, s3));
        float e0 = __expf(s0-mm), e1 = __expf(s1-mm), e2 = __expf(s2-mm), e3 = __expf(s3-mm);
        float inv = 1.0f/(e0+e1+e2+e3);
        float av0 = e0*inv, av1 = e1*inv, av2 = e2*inv, av3 = e3*inv;
        #pragma unroll
        for (int k = 0; k < 8; k += 2) {
          float cv0 = av0*cls0[k] + av1*cls1[k] + av2*cls2[k] + av3*cls3[k];
          float cv1 = av0*cls0[k+1] + av1*cls1[k+1] + av2*cls2[k+1] + av3*cls3[k+1];
          split2x2(cv0, cv1, ch.u[k>>1], cl.u[k>>1]);
        }
        int o = cbBase + ((eg*8) ^ swc);
        *(uint2*)&CBhi[o]     = ch.d[0]; *(uint2*)&CBhi[o + 4] = ch.d[1];
        *(uint2*)&CBlo[o]     = cl.d[0]; *(uint2*)&CBlo[o + 4] = cl.d[1];
      }
      {
        float s0 = q0*SCALE_RA, s1 = q1*SCALE_RA, s2 = q2*SCALE_RA, s3 = q3*SCALE_RA;
        float mm = fmaxf(fmaxf(s0, s1), fmaxf(s2, s3));
        float e0 = __expf(s0-mm), e1 = __expf(s1-mm), e2 = __expf(s2-mm), e3 = __expf(s3-mm);
        float inv = 1.0f/(e0+e1+e2+e3);
        float av0 = e0*inv, av1 = e1*inv, av2 = e2*inv, av3 = e3*inv;
        #pragma unroll
        for (int k = 0; k < 8; k += 2) {
          float cv0 = av0*cls0[k] + av1*cls1[k] + av2*cls2[k] + av3*cls3[k];
          float cv1 = av0*cls0[k+1] + av1*cls1[k+1] + av2*cls2[k+1] + av3*cls3[k+1];
          split2x2(cv0, cv1, ch.u[k>>1], cl.u[k>>1]);
        }
        int o = cbBase + ((64 + eg*8) ^ swc);
        *(uint2*)&CBhi[o]     = ch.d[0]; *(uint2*)&CBhi[o + 4] = ch.d[1];
        *(uint2*)&CBlo[o]     = cl.d[0]; *(uint2*)&CBlo[o + 4] = cl.d[1];
      }
    }
    __syncthreads();
    // ---- stage3: OUT(16x64) += CB(16x128) @ [Zt_h0 ; Zt_h1] ----
    {
      #pragma unroll
      for (int c = 0; c < 2; ++c) {
        int colb = wcol*2 + c;                  // 0..3
        int e0 = colb*16 + lrow;                // 0..63
        f32x4 acc = (c == 0) ? oa0 : oa1;
        #pragma unroll
        for (int kb = 0; kb < 4; ++kb) {
          union { bf16x8 v; uint2 d[2]; } ah, al;
          int o = (kb*32 + quad*8) ^ sw3;
          ah.d[0] = *(const uint2*)(crh + o); ah.d[1] = *(const uint2*)(crh + o + 4);
          al.d[0] = *(const uint2*)(crl + o); al.d[1] = *(const uint2*)(crl + o + 4);
          // fragment-swizzled Z: record = h*8192 + colb*2048 + kb1*1024 (+512 lo)
          const unsigned short* zc = zball + (h0 + (kb >> 1))*8192 + colb*2048 + (kb & 1)*1024 + lane*8;
          bf16x8 bh = *(const bf16x8*)(zc);
          bf16x8 bl = *(const bf16x8*)(zc + 512);
          __builtin_amdgcn_s_setprio(1);
          acc = __builtin_amdgcn_mfma_f32_16x16x32_bf16(ah.v, bh, acc, 0, 0, 0);
          acc = __builtin_amdgcn_mfma_f32_16x16x32_bf16(al.v, bh, acc, 0, 0, 0);
          acc = __builtin_amdgcn_mfma_f32_16x16x32_bf16(ah.v, bl, acc, 0, 0, 0);
          __builtin_amdgcn_s_setprio(0);
        }
        if (c == 0) oa0 = acc; else oa1 = acc;
      }
    }
  }
  // epilogue
  #pragma unroll
  for (int c = 0; c < 2; ++c) {
    int e0 = (wcol*2 + c)*16 + lrow;
    float cov = ws[OFF_C1 + e0];
    f32x4 oa = (c == 0) ? oa0 : oa1;
    #pragma unroll
    for (int r = 0; r < 4; ++r)
      outp[(T0 + quad*4 + r)*64 + e0] = oa[r] + cov;
  }
}

extern "C" void kernel_launch(void* const* d_in, const int* in_sizes, int n_in,
                              void* d_out, int out_size, void* d_ws, size_t ws_size,
                              hipStream_t stream) {
  const float* x      = (const float*)d_in[0];
  const float* ln_g   = (const float*)d_in[1];
  const float* ln_b   = (const float*)d_in[2];
  const float* Wqkv   = (const float*)d_in[3];
  const float* bqkv   = (const float*)d_in[4];
  const float* cls_tok= (const float*)d_in[5];
  const float* Wwqkv  = (const float*)d_in[6];
  const float* bwqkv  = (const float*)d_in[7];
  const float* Wwproj = (const float*)d_in[8];
  const float* bwproj = (const float*)d_in[9];
  const float* Wraq   = (const float*)d_in[10];
  const float* Wrak   = (const float*)d_in[11];
  const float* Wrav   = (const float*)d_in[12];
  const float* Wrao   = (const float*)d_in[13];
  const float* brao   = (const float*)d_in[14];
  const float* Wout   = (const float*)d_in[15];
  const float* bout   = (const float*)d_in[16];
  float* ws = (float*)d_ws;
  float* outp = (float*)d_out;

  hipLaunchKernelGGL(k_pre, dim3(2321), dim3(256), 0, stream,
                     x, ln_g, ln_b, Wqkv, bqkv, cls_tok, Wwqkv, bwqkv,
                     Wwproj, bwproj, Wraq, Wrak, Wrav, Wrao, brao, Wout, bout, ws);
  hipLaunchKernelGGL(k_prefix, dim3(512), dim3(512), 0, stream, ws);
  hipLaunchKernelGGL(k_main, dim3(9216), dim3(128), 0, stream, x, ln_g, ln_b, ws, outp);
}